// Round 1
// baseline (552.095 us; speedup 1.0000x reference)
//
#include <hip/hip_runtime.h>

#define NN 16384
#define EE 262144
#define GG 32
#define NPGC 512
#define NEG_SLOPE 0.2f

// ---------------- build h = [aa_emb[ref]*aa_emb[alt[gid]] | feat] ----------------
__global__ __launch_bounds__(320) void build_h_kernel(
    const float* __restrict__ feat, const float* __restrict__ aa_emb,
    const int* __restrict__ ref_aa, const int* __restrict__ alt_aa,
    const int* __restrict__ graph_id, float* __restrict__ h)
{
    int n = blockIdx.x, t = threadIdx.x;
    float v;
    if (t < 64) {
        int ra = ref_aa[n], ga = alt_aa[graph_id[n]];
        v = aa_emb[ra * 64 + t] * aa_emb[ga * 64 + t];
    } else {
        v = feat[(size_t)n * 256 + (t - 64)];
    }
    h[(size_t)n * 320 + t] = v;
}

// ---------------- CSR build ----------------
__global__ __launch_bounds__(256) void deg_kernel(const int* __restrict__ dst, int* __restrict__ deg)
{
    int i = blockIdx.x * 256 + threadIdx.x;
    if (i < EE) atomicAdd(&deg[dst[i]], 1);
}

__global__ __launch_bounds__(256) void scan_kernel(const int* __restrict__ deg,
                                                   int* __restrict__ row, int* __restrict__ cursor)
{
    __shared__ int part[256];
    __shared__ int pref[257];
    int t = threadIdx.x, base = t * 64;
    int s = 0;
    for (int i = 0; i < 64; i++) s += deg[base + i];
    part[t] = s;
    __syncthreads();
    if (t == 0) {
        int a = 0;
        for (int i = 0; i < 256; i++) { pref[i] = a; a += part[i]; }
        pref[256] = a;
    }
    __syncthreads();
    int a = pref[t];
    for (int i = 0; i < 64; i++) {
        row[base + i] = a; cursor[base + i] = a;
        a += deg[base + i];
    }
    if (t == 0) row[NN] = pref[256];
}

__global__ __launch_bounds__(256) void scatter_kernel(const int* __restrict__ dst,
                                                      int* __restrict__ cursor, int* __restrict__ eid)
{
    int i = blockIdx.x * 256 + threadIdx.x;
    if (i < EE) {
        int p = atomicAdd(&cursor[dst[i]], 1);
        eid[p] = i;
    }
}

// ---------------- generic row-blocked GEMM: out[N, 256*CPT] = A[N,K] @ [B1|B2] ----------------
template<int K, int CPT>
__global__ __launch_bounds__(256) void gemm_cat_kernel(
    const float* __restrict__ A, const float* __restrict__ B1, int c1,
    const float* __restrict__ B2, int c2, float* __restrict__ out)
{
    const int CT = 256 * CPT;
    __shared__ float As[8 * K];
    int r0 = blockIdx.x * 8;
    int t = threadIdx.x;
    for (int i = t; i < 8 * K; i += 256) As[i] = A[(size_t)r0 * K + i];
    __syncthreads();

    const float* bp[CPT];
    int st[CPT];
#pragma unroll
    for (int j = 0; j < CPT; j++) {
        int c = t + j * 256;
        if (c < c1) { bp[j] = B1 + c; st[j] = c1; }
        else        { bp[j] = B2 + (c - c1); st[j] = c2; }
    }
    float acc[8][CPT];
#pragma unroll
    for (int r = 0; r < 8; r++)
#pragma unroll
        for (int j = 0; j < CPT; j++) acc[r][j] = 0.f;

    for (int k = 0; k < K; k++) {
        float w[CPT];
#pragma unroll
        for (int j = 0; j < CPT; j++) { w[j] = *bp[j]; bp[j] += st[j]; }
#pragma unroll
        for (int r = 0; r < 8; r++) {
            float a = As[r * K + k];
#pragma unroll
            for (int j = 0; j < CPT; j++) acc[r][j] += a * w[j];
        }
    }
#pragma unroll
    for (int r = 0; r < 8; r++)
#pragma unroll
        for (int j = 0; j < CPT; j++)
            out[(size_t)(r0 + r) * CT + t + j * 256] = acc[r][j];
}

// ---------------- el/er per (node, head): el = <ft[n,h,:], al[h,:]> ----------------
template<int O>
__global__ __launch_bounds__(256) void elr_kernel(
    const float* __restrict__ ftrr, int ldft,
    const float* __restrict__ al, const float* __restrict__ ar,
    float* __restrict__ el, float* __restrict__ er)
{
    int gid = blockIdx.x * 256 + threadIdx.x;
    int wv = gid >> 6, lane = gid & 63;
    int n = wv >> 1, hh = wv & 1;
    if (n >= NN) return;
    float sl = 0.f, sr = 0.f;
#pragma unroll
    for (int j = 0; j < O / 64; j++) {
        int o = j * 64 + lane;
        float f = ftrr[(size_t)n * ldft + hh * O + o];
        sl += f * al[hh * O + o];
        sr += f * ar[hh * O + o];
    }
#pragma unroll
    for (int d = 32; d; d >>= 1) { sl += __shfl_xor(sl, d); sr += __shfl_xor(sr, d); }
    if (lane == 0) { el[n * 2 + hh] = sl; er[n * 2 + hh] = sr; }
}

// ---------------- layer0 aggregation + res + bias + ELU -> h1[N,128] ----------------
__global__ __launch_bounds__(128) void agg0_kernel(
    const float* __restrict__ ftrr0, const int* __restrict__ row,
    const int* __restrict__ eid, const int* __restrict__ src,
    const float* __restrict__ el, const float* __restrict__ er,
    const float* __restrict__ b0, float* __restrict__ h1)
{
    int n = blockIdx.x, t = threadIdx.x;
    int hh = t >> 6, o = t & 63;
    int e0 = row[n], e1 = row[n + 1];
    float ern = er[n * 2 + hh];

    float m = -1e30f;
    for (int i = e0; i < e1; i++) {
        int s = src[eid[i]];
        float ev = el[s * 2 + hh] + ern;
        ev = ev > 0.f ? ev : NEG_SLOPE * ev;
        m = fmaxf(m, ev);
    }
    float acc = 0.f, ssum = 0.f;
    for (int i = e0; i < e1; i++) {
        int s = src[eid[i]];
        float ev = el[s * 2 + hh] + ern;
        ev = ev > 0.f ? ev : NEG_SLOPE * ev;
        float wgt = __expf(ev - m);
        ssum += wgt;
        acc += wgt * ftrr0[(size_t)s * 256 + hh * 64 + o];
    }
    float r = (e1 > e0 ? acc / ssum : 0.f)
            + ftrr0[(size_t)n * 256 + 128 + hh * 64 + o] + b0[hh * 64 + o];
    h1[(size_t)n * 128 + t] = r > 0.f ? r : (__expf(r) - 1.f);
}

// ---------------- layer1 aggregation + res + bias + head-mean + ELU -> h2[N,256] ----------------
__global__ __launch_bounds__(512) void agg1_kernel(
    const float* __restrict__ ftrr1, const int* __restrict__ row,
    const int* __restrict__ eid, const int* __restrict__ src,
    const float* __restrict__ el, const float* __restrict__ er,
    const float* __restrict__ b1, float* __restrict__ h2)
{
    __shared__ float tmp[256];
    int n = blockIdx.x, t = threadIdx.x;
    int hh = t >> 8, o = t & 255;
    int e0 = row[n], e1 = row[n + 1];
    float ern = er[n * 2 + hh];

    float m = -1e30f;
    for (int i = e0; i < e1; i++) {
        int s = src[eid[i]];
        float ev = el[s * 2 + hh] + ern;
        ev = ev > 0.f ? ev : NEG_SLOPE * ev;
        m = fmaxf(m, ev);
    }
    float acc = 0.f, ssum = 0.f;
    for (int i = e0; i < e1; i++) {
        int s = src[eid[i]];
        float ev = el[s * 2 + hh] + ern;
        ev = ev > 0.f ? ev : NEG_SLOPE * ev;
        float wgt = __expf(ev - m);
        ssum += wgt;
        acc += wgt * ftrr1[(size_t)s * 1024 + hh * 256 + o];
    }
    float r = (e1 > e0 ? acc / ssum : 0.f)
            + ftrr1[(size_t)n * 1024 + 512 + hh * 256 + o] + b1[hh * 256 + o];
    if (hh == 1) tmp[o] = r;
    __syncthreads();
    if (hh == 0) {
        float v = 0.5f * (r + tmp[o]);
        h2[(size_t)n * 256 + o] = v > 0.f ? v : (__expf(v) - 1.f);
    }
}

// ---------------- per-graph mean readout + 3-layer MLP ----------------
__global__ __launch_bounds__(256) void readout_mlp_kernel(
    const float* __restrict__ h2,
    const float* __restrict__ mW0, const float* __restrict__ mb0,
    const float* __restrict__ mW1, const float* __restrict__ mb1,
    const float* __restrict__ mW2, const float* __restrict__ mb2,
    float* __restrict__ out)
{
    __shared__ float hg[256];
    __shared__ float x1[128];
    __shared__ float x2[64];
    int g = blockIdx.x, t = threadIdx.x;
    float s = 0.f;
    for (int i = 0; i < NPGC; i++) s += h2[(size_t)(g * NPGC + i) * 256 + t];
    hg[t] = s * (1.f / (float)NPGC);
    __syncthreads();
    if (t < 128) {
        float a = mb0[t];
        for (int k = 0; k < 256; k++) a += hg[k] * mW0[k * 128 + t];
        x1[t] = fmaxf(a, 0.f);
    }
    __syncthreads();
    if (t < 64) {
        float a = mb1[t];
        for (int k = 0; k < 128; k++) a += x1[k] * mW1[k * 64 + t];
        x2[t] = fmaxf(a, 0.f);
    }
    __syncthreads();
    if (t < 2) {
        float a = mb2[t];
        for (int k = 0; k < 64; k++) a += x2[k] * mW2[k * 2 + t];
        out[g * 2 + t] = a;
    }
}

extern "C" void kernel_launch(void* const* d_in, const int* in_sizes, int n_in,
                              void* d_out, int out_size, void* d_ws, size_t ws_size,
                              hipStream_t stream)
{
    const float* feat   = (const float*)d_in[0];
    const float* aa_emb = (const float*)d_in[1];
    const float* W0     = (const float*)d_in[2];
    const float* al0    = (const float*)d_in[3];
    const float* ar0    = (const float*)d_in[4];
    const float* res0   = (const float*)d_in[5];
    const float* b0     = (const float*)d_in[6];
    const float* W1     = (const float*)d_in[7];
    const float* al1    = (const float*)d_in[8];
    const float* ar1    = (const float*)d_in[9];
    const float* res1   = (const float*)d_in[10];
    const float* b1     = (const float*)d_in[11];
    const float* mW0    = (const float*)d_in[12];
    const float* mb0    = (const float*)d_in[13];
    const float* mW1    = (const float*)d_in[14];
    const float* mb1    = (const float*)d_in[15];
    const float* mW2    = (const float*)d_in[16];
    const float* mb2    = (const float*)d_in[17];
    const int* ref_aa   = (const int*)d_in[18];
    const int* alt_aa   = (const int*)d_in[19];
    const int* src      = (const int*)d_in[20];
    const int* dst      = (const int*)d_in[21];
    const int* graph_id = (const int*)d_in[22];
    float* out = (float*)d_out;

    // workspace layout (~116 MB)
    size_t off = 0;
    auto alloc = [&](size_t bytes) -> void* {
        void* p = (char*)d_ws + off;
        off += (bytes + 255) & ~(size_t)255;
        return p;
    };
    float* h     = (float*)alloc((size_t)NN * 320 * 4);
    float* ftrr0 = (float*)alloc((size_t)NN * 256 * 4);
    float* h1    = (float*)alloc((size_t)NN * 128 * 4);
    float* ftrr1 = (float*)alloc((size_t)NN * 1024 * 4);
    float* el0   = (float*)alloc((size_t)NN * 2 * 4);
    float* er0   = (float*)alloc((size_t)NN * 2 * 4);
    float* el1   = (float*)alloc((size_t)NN * 2 * 4);
    float* er1   = (float*)alloc((size_t)NN * 2 * 4);
    int* deg     = (int*)alloc((size_t)NN * 4);
    int* row     = (int*)alloc((size_t)(NN + 1) * 4);
    int* cursor  = (int*)alloc((size_t)NN * 4);
    int* eid     = (int*)alloc((size_t)EE * 4);
    float* h2    = h;   // h is dead after gemm0; reuse its space

    (void)in_sizes; (void)n_in; (void)out_size; (void)ws_size;

    hipMemsetAsync(deg, 0, (size_t)NN * 4, stream);
    build_h_kernel<<<NN, 320, 0, stream>>>(feat, aa_emb, ref_aa, alt_aa, graph_id, h);
    deg_kernel<<<EE / 256, 256, 0, stream>>>(dst, deg);
    scan_kernel<<<1, 256, 0, stream>>>(deg, row, cursor);
    scatter_kernel<<<EE / 256, 256, 0, stream>>>(dst, cursor, eid);

    // layer 0: ftrr0 = h @ [W0 | res0]
    gemm_cat_kernel<320, 1><<<NN / 8, 256, 0, stream>>>(h, W0, 128, res0, 128, ftrr0);
    elr_kernel<64><<<(NN * 2 * 64) / 256, 256, 0, stream>>>(ftrr0, 256, al0, ar0, el0, er0);
    agg0_kernel<<<NN, 128, 0, stream>>>(ftrr0, row, eid, src, el0, er0, b0, h1);

    // layer 1: ftrr1 = h1 @ [W1 | res1]
    gemm_cat_kernel<128, 4><<<NN / 8, 256, 0, stream>>>(h1, W1, 512, res1, 512, ftrr1);
    elr_kernel<256><<<(NN * 2 * 64) / 256, 256, 0, stream>>>(ftrr1, 1024, al1, ar1, el1, er1);
    agg1_kernel<<<NN, 512, 0, stream>>>(ftrr1, row, eid, src, el1, er1, b1, h2);

    // readout + MLP
    readout_mlp_kernel<<<GG, 256, 0, stream>>>(h2, mW0, mb0, mW1, mb1, mW2, mb2, out);
}

// Round 2
// 322.196 us; speedup vs baseline: 1.7135x; 1.7135x over previous
//
#include <hip/hip_runtime.h>
#include <hip/hip_bf16.h>

#define NN 16384
#define EE 262144
#define GG 32
#define NPGC 512
#define NEG_SLOPE 0.2f

// ---------------- build h = [aa_emb[ref]*aa_emb[alt[gid]] | feat] ----------------
__global__ __launch_bounds__(320) void build_h_kernel(
    const float* __restrict__ feat, const float* __restrict__ aa_emb,
    const int* __restrict__ ref_aa, const int* __restrict__ alt_aa,
    const int* __restrict__ graph_id, float* __restrict__ h)
{
    int n = blockIdx.x, t = threadIdx.x;
    float v;
    if (t < 64) {
        int ra = ref_aa[n], ga = alt_aa[graph_id[n]];
        v = aa_emb[ra * 64 + t] * aa_emb[ga * 64 + t];
    } else {
        v = feat[(size_t)n * 256 + (t - 64)];
    }
    h[(size_t)n * 320 + t] = v;
}

// ---------------- CSR build ----------------
__global__ __launch_bounds__(256) void deg_kernel(const int* __restrict__ dst, int* __restrict__ deg)
{
    int i = blockIdx.x * 256 + threadIdx.x;
    if (i < EE) atomicAdd(&deg[dst[i]], 1);
}

__global__ __launch_bounds__(256) void scan_kernel(const int* __restrict__ deg,
                                                   int* __restrict__ row, int* __restrict__ cursor)
{
    __shared__ int part[256];
    __shared__ int pref[257];
    int t = threadIdx.x, base = t * 64;
    int s = 0;
    for (int i = 0; i < 64; i++) s += deg[base + i];
    part[t] = s;
    __syncthreads();
    if (t == 0) {
        int a = 0;
        for (int i = 0; i < 256; i++) { pref[i] = a; a += part[i]; }
        pref[256] = a;
    }
    __syncthreads();
    int a = pref[t];
    for (int i = 0; i < 64; i++) {
        row[base + i] = a; cursor[base + i] = a;
        a += deg[base + i];
    }
    if (t == 0) row[NN] = pref[256];
}

__global__ __launch_bounds__(256) void scatter_kernel(const int* __restrict__ dst,
                                                      int* __restrict__ cursor, int* __restrict__ eid)
{
    int i = blockIdx.x * 256 + threadIdx.x;
    if (i < EE) {
        int p = atomicAdd(&cursor[dst[i]], 1);
        eid[p] = i;
    }
}

// ---------------- GEMM: [ftb(bf16) | resf(f32)] = A[N,K] @ [B1 | B2], each C1 cols ----------------
template<int K, int CPT, int C1>
__global__ __launch_bounds__(256) void gemm_split_kernel(
    const float* __restrict__ A, const float* __restrict__ B1,
    const float* __restrict__ B2, __hip_bfloat16* __restrict__ ftb,
    float* __restrict__ resf)
{
    __shared__ float As[8 * K];
    int r0 = blockIdx.x * 8;
    int t = threadIdx.x;
    for (int i = t; i < 8 * K; i += 256) As[i] = A[(size_t)r0 * K + i];
    __syncthreads();

    const float* bp[CPT];
#pragma unroll
    for (int j = 0; j < CPT; j++) {
        int c = t + j * 256;
        bp[j] = (c < C1) ? (B1 + c) : (B2 + (c - C1));
    }
    float acc[8][CPT];
#pragma unroll
    for (int r = 0; r < 8; r++)
#pragma unroll
        for (int j = 0; j < CPT; j++) acc[r][j] = 0.f;

    for (int k = 0; k < K; k++) {
        float w[CPT];
#pragma unroll
        for (int j = 0; j < CPT; j++) { w[j] = *bp[j]; bp[j] += C1; }
#pragma unroll
        for (int r = 0; r < 8; r++) {
            float a = As[r * K + k];
#pragma unroll
            for (int j = 0; j < CPT; j++) acc[r][j] += a * w[j];
        }
    }
#pragma unroll
    for (int r = 0; r < 8; r++)
#pragma unroll
        for (int j = 0; j < CPT; j++) {
            int c = t + j * 256;
            if (c < C1) ftb[(size_t)(r0 + r) * C1 + c] = __float2bfloat16(acc[r][j]);
            else        resf[(size_t)(r0 + r) * C1 + (c - C1)] = acc[r][j];
        }
}

// ---------------- el/er per (node, head) from bf16 ft ----------------
template<int O>
__global__ __launch_bounds__(256) void elr_kernel(
    const __hip_bfloat16* __restrict__ ftb, int ldft,
    const float* __restrict__ al, const float* __restrict__ ar,
    float* __restrict__ el, float* __restrict__ er)
{
    int gid = blockIdx.x * 256 + threadIdx.x;
    int wv = gid >> 6, lane = gid & 63;
    int n = wv >> 1, hh = wv & 1;
    if (n >= NN) return;
    float sl = 0.f, sr = 0.f;
#pragma unroll
    for (int j = 0; j < O / 64; j++) {
        int o = j * 64 + lane;
        float f = __bfloat162float(ftb[(size_t)n * ldft + hh * O + o]);
        sl += f * al[hh * O + o];
        sr += f * ar[hh * O + o];
    }
#pragma unroll
    for (int d = 32; d; d >>= 1) { sl += __shfl_xor(sl, d); sr += __shfl_xor(sr, d); }
    if (lane == 0) { el[n * 2 + hh] = sl; er[n * 2 + hh] = sr; }
}

// ---------------- edge softmax weights: one wave per node, lanes over edges ----------------
// Writes unnormalized w=exp(e-max) per (edge,head) and inv[n][h]=1/sum.
template<bool FIRST>
__global__ __launch_bounds__(256) void alpha_kernel(
    const int* __restrict__ row, const int* __restrict__ eid,
    const int* __restrict__ src, int* __restrict__ srcs,
    const float* __restrict__ el, const float* __restrict__ er,
    float* __restrict__ alpha, float* __restrict__ inv)
{
    int gid = blockIdx.x * 256 + threadIdx.x;
    int n = gid >> 6, lane = gid & 63;
    if (n >= NN) return;
    int e0 = row[n], e1 = row[n + 1];
    float er0v = er[n * 2 + 0], er1v = er[n * 2 + 1];

    float m0 = -1e30f, m1 = -1e30f;
    for (int p = e0 + lane; p < e1; p += 64) {
        int s;
        if (FIRST) { s = src[eid[p]]; srcs[p] = s; }
        else       { s = srcs[p]; }
        float v0 = el[s * 2 + 0] + er0v; v0 = v0 > 0.f ? v0 : NEG_SLOPE * v0;
        float v1 = el[s * 2 + 1] + er1v; v1 = v1 > 0.f ? v1 : NEG_SLOPE * v1;
        m0 = fmaxf(m0, v0); m1 = fmaxf(m1, v1);
    }
#pragma unroll
    for (int d = 32; d; d >>= 1) {
        m0 = fmaxf(m0, __shfl_xor(m0, d));
        m1 = fmaxf(m1, __shfl_xor(m1, d));
    }
    float s0 = 0.f, s1 = 0.f;
    for (int p = e0 + lane; p < e1; p += 64) {
        int s = srcs[p];
        float v0 = el[s * 2 + 0] + er0v; v0 = v0 > 0.f ? v0 : NEG_SLOPE * v0;
        float v1 = el[s * 2 + 1] + er1v; v1 = v1 > 0.f ? v1 : NEG_SLOPE * v1;
        float w0 = __expf(v0 - m0), w1 = __expf(v1 - m1);
        alpha[p * 2 + 0] = w0; alpha[p * 2 + 1] = w1;
        s0 += w0; s1 += w1;
    }
#pragma unroll
    for (int d = 32; d; d >>= 1) { s0 += __shfl_xor(s0, d); s1 += __shfl_xor(s1, d); }
    if (lane == 0) {
        inv[n * 2 + 0] = s0 > 0.f ? 1.f / s0 : 0.f;
        inv[n * 2 + 1] = s1 > 0.f ? 1.f / s1 : 0.f;
    }
}

// ---------------- layer0 aggregation: h1[N,128] ----------------
__global__ __launch_bounds__(128) void agg0_kernel(
    const __hip_bfloat16* __restrict__ ftb0, const float* __restrict__ resf0,
    const int* __restrict__ row, const int* __restrict__ srcs,
    const float* __restrict__ alpha, const float* __restrict__ inv,
    const float* __restrict__ b0, float* __restrict__ h1)
{
    __shared__ int s_src[128];
    __shared__ float s_a[256];
    int n = blockIdx.x, t = threadIdx.x;
    int hh = t >> 6, o = t & 63;
    int e0 = row[n], e1 = row[n + 1];
    float acc = 0.f;
    for (int base = e0; base < e1; base += 128) {
        int c = min(128, e1 - base);
        __syncthreads();
        if (t < c) s_src[t] = srcs[base + t];
        if (t < 2 * c) s_a[t] = alpha[base * 2 + t];
        __syncthreads();
        int i = 0;
        for (; i + 4 <= c; i += 4) {
            int n0 = s_src[i], n1 = s_src[i + 1], n2 = s_src[i + 2], n3 = s_src[i + 3];
            float a0 = s_a[2 * i + hh],       a1 = s_a[2 * (i + 1) + hh];
            float a2 = s_a[2 * (i + 2) + hh], a3 = s_a[2 * (i + 3) + hh];
            float f0 = __bfloat162float(ftb0[(size_t)n0 * 128 + t]);
            float f1 = __bfloat162float(ftb0[(size_t)n1 * 128 + t]);
            float f2 = __bfloat162float(ftb0[(size_t)n2 * 128 + t]);
            float f3 = __bfloat162float(ftb0[(size_t)n3 * 128 + t]);
            acc += a0 * f0; acc += a1 * f1; acc += a2 * f2; acc += a3 * f3;
        }
        for (; i < c; i++) {
            acc += s_a[2 * i + hh] * __bfloat162float(ftb0[(size_t)s_src[i] * 128 + t]);
        }
    }
    float r = acc * inv[n * 2 + hh] + resf0[(size_t)n * 128 + t] + b0[t];
    h1[(size_t)n * 128 + t] = r > 0.f ? r : (__expf(r) - 1.f);
}

// ---------------- layer1 aggregation + head-mean + ELU: h2[N,256] ----------------
__global__ __launch_bounds__(512) void agg1_kernel(
    const __hip_bfloat16* __restrict__ ftb1, const float* __restrict__ resf1,
    const int* __restrict__ row, const int* __restrict__ srcs,
    const float* __restrict__ alpha, const float* __restrict__ inv,
    const float* __restrict__ b1, float* __restrict__ h2)
{
    __shared__ int s_src[256];
    __shared__ float s_a[512];
    __shared__ float tmp[256];
    int n = blockIdx.x, t = threadIdx.x;
    int hh = t >> 8, o = t & 255;
    int e0 = row[n], e1 = row[n + 1];
    float acc = 0.f;
    for (int base = e0; base < e1; base += 256) {
        int c = min(256, e1 - base);
        __syncthreads();
        if (t < c) s_src[t] = srcs[base + t];
        if (t < 2 * c) s_a[t] = alpha[base * 2 + t];
        __syncthreads();
        int i = 0;
        for (; i + 4 <= c; i += 4) {
            int n0 = s_src[i], n1 = s_src[i + 1], n2 = s_src[i + 2], n3 = s_src[i + 3];
            float a0 = s_a[2 * i + hh],       a1 = s_a[2 * (i + 1) + hh];
            float a2 = s_a[2 * (i + 2) + hh], a3 = s_a[2 * (i + 3) + hh];
            float f0 = __bfloat162float(ftb1[(size_t)n0 * 512 + hh * 256 + o]);
            float f1 = __bfloat162float(ftb1[(size_t)n1 * 512 + hh * 256 + o]);
            float f2 = __bfloat162float(ftb1[(size_t)n2 * 512 + hh * 256 + o]);
            float f3 = __bfloat162float(ftb1[(size_t)n3 * 512 + hh * 256 + o]);
            acc += a0 * f0; acc += a1 * f1; acc += a2 * f2; acc += a3 * f3;
        }
        for (; i < c; i++) {
            acc += s_a[2 * i + hh] * __bfloat162float(ftb1[(size_t)s_src[i] * 512 + hh * 256 + o]);
        }
    }
    float r = acc * inv[n * 2 + hh] + resf1[(size_t)n * 512 + hh * 256 + o] + b1[hh * 256 + o];
    if (hh == 1) tmp[o] = r;
    __syncthreads();
    if (hh == 0) {
        float v = 0.5f * (r + tmp[o]);
        h2[(size_t)n * 256 + o] = v > 0.f ? v : (__expf(v) - 1.f);
    }
}

// ---------------- per-graph mean readout + 3-layer MLP ----------------
__global__ __launch_bounds__(256) void readout_mlp_kernel(
    const float* __restrict__ h2,
    const float* __restrict__ mW0, const float* __restrict__ mb0,
    const float* __restrict__ mW1, const float* __restrict__ mb1,
    const float* __restrict__ mW2, const float* __restrict__ mb2,
    float* __restrict__ out)
{
    __shared__ float hg[256];
    __shared__ float x1[128];
    __shared__ float x2[64];
    int g = blockIdx.x, t = threadIdx.x;
    float s = 0.f;
    for (int i = 0; i < NPGC; i++) s += h2[(size_t)(g * NPGC + i) * 256 + t];
    hg[t] = s * (1.f / (float)NPGC);
    __syncthreads();
    if (t < 128) {
        float a = mb0[t];
        for (int k = 0; k < 256; k++) a += hg[k] * mW0[k * 128 + t];
        x1[t] = fmaxf(a, 0.f);
    }
    __syncthreads();
    if (t < 64) {
        float a = mb1[t];
        for (int k = 0; k < 128; k++) a += x1[k] * mW1[k * 64 + t];
        x2[t] = fmaxf(a, 0.f);
    }
    __syncthreads();
    if (t < 2) {
        float a = mb2[t];
        for (int k = 0; k < 64; k++) a += x2[k] * mW2[k * 2 + t];
        out[g * 2 + t] = a;
    }
}

extern "C" void kernel_launch(void* const* d_in, const int* in_sizes, int n_in,
                              void* d_out, int out_size, void* d_ws, size_t ws_size,
                              hipStream_t stream)
{
    const float* feat   = (const float*)d_in[0];
    const float* aa_emb = (const float*)d_in[1];
    const float* W0     = (const float*)d_in[2];
    const float* al0    = (const float*)d_in[3];
    const float* ar0    = (const float*)d_in[4];
    const float* res0   = (const float*)d_in[5];
    const float* b0     = (const float*)d_in[6];
    const float* W1     = (const float*)d_in[7];
    const float* al1    = (const float*)d_in[8];
    const float* ar1    = (const float*)d_in[9];
    const float* res1   = (const float*)d_in[10];
    const float* b1     = (const float*)d_in[11];
    const float* mW0    = (const float*)d_in[12];
    const float* mb0    = (const float*)d_in[13];
    const float* mW1    = (const float*)d_in[14];
    const float* mb1    = (const float*)d_in[15];
    const float* mW2    = (const float*)d_in[16];
    const float* mb2    = (const float*)d_in[17];
    const int* ref_aa   = (const int*)d_in[18];
    const int* alt_aa   = (const int*)d_in[19];
    const int* src      = (const int*)d_in[20];
    const int* dst      = (const int*)d_in[21];
    const int* graph_id = (const int*)d_in[22];
    float* out = (float*)d_out;

    size_t off = 0;
    auto alloc = [&](size_t bytes) -> void* {
        void* p = (char*)d_ws + off;
        off += (bytes + 255) & ~(size_t)255;
        return p;
    };
    float* h      = (float*)alloc((size_t)NN * 320 * 4);
    __hip_bfloat16* ftb0 = (__hip_bfloat16*)alloc((size_t)NN * 128 * 2);
    float* resf0  = (float*)alloc((size_t)NN * 128 * 4);
    float* h1     = (float*)alloc((size_t)NN * 128 * 4);
    __hip_bfloat16* ftb1 = (__hip_bfloat16*)alloc((size_t)NN * 512 * 2);
    float* resf1  = (float*)alloc((size_t)NN * 512 * 4);
    float* el0    = (float*)alloc((size_t)NN * 2 * 4);
    float* er0    = (float*)alloc((size_t)NN * 2 * 4);
    float* el1    = (float*)alloc((size_t)NN * 2 * 4);
    float* er1    = (float*)alloc((size_t)NN * 2 * 4);
    float* inv0   = (float*)alloc((size_t)NN * 2 * 4);
    float* inv1   = (float*)alloc((size_t)NN * 2 * 4);
    int* deg      = (int*)alloc((size_t)NN * 4);
    int* row      = (int*)alloc((size_t)(NN + 1) * 4);
    int* cursor   = (int*)alloc((size_t)NN * 4);
    int* eid      = (int*)alloc((size_t)EE * 4);
    int* srcs     = (int*)alloc((size_t)EE * 4);
    float* alpha0 = (float*)alloc((size_t)EE * 2 * 4);
    float* alpha1 = (float*)alloc((size_t)EE * 2 * 4);
    float* h2     = h;   // h is dead after gemm0; reuse its space

    (void)in_sizes; (void)n_in; (void)out_size; (void)ws_size;

    hipMemsetAsync(deg, 0, (size_t)NN * 4, stream);
    build_h_kernel<<<NN, 320, 0, stream>>>(feat, aa_emb, ref_aa, alt_aa, graph_id, h);
    deg_kernel<<<EE / 256, 256, 0, stream>>>(dst, deg);
    scan_kernel<<<1, 256, 0, stream>>>(deg, row, cursor);
    scatter_kernel<<<EE / 256, 256, 0, stream>>>(dst, cursor, eid);

    // layer 0
    gemm_split_kernel<320, 1, 128><<<NN / 8, 256, 0, stream>>>(h, W0, res0, ftb0, resf0);
    elr_kernel<64><<<(NN * 2 * 64) / 256, 256, 0, stream>>>(ftb0, 128, al0, ar0, el0, er0);
    alpha_kernel<true><<<NN / 4, 256, 0, stream>>>(row, eid, src, srcs, el0, er0, alpha0, inv0);
    agg0_kernel<<<NN, 128, 0, stream>>>(ftb0, resf0, row, srcs, alpha0, inv0, b0, h1);

    // layer 1
    gemm_split_kernel<128, 4, 512><<<NN / 8, 256, 0, stream>>>(h1, W1, res1, ftb1, resf1);
    elr_kernel<256><<<(NN * 2 * 64) / 256, 256, 0, stream>>>(ftb1, 512, al1, ar1, el1, er1);
    alpha_kernel<false><<<NN / 4, 256, 0, stream>>>(row, eid, src, srcs, el1, er1, alpha1, inv1);
    agg1_kernel<<<NN, 512, 0, stream>>>(ftb1, resf1, row, srcs, alpha1, inv1, b1, h2);

    // readout + MLP
    readout_mlp_kernel<<<GG, 256, 0, stream>>>(h2, mW0, mb0, mW1, mb1, mW2, mb2, out);
}

// Round 3
// 227.658 us; speedup vs baseline: 2.4251x; 1.4153x over previous
//
#include <hip/hip_runtime.h>
#include <hip/hip_bf16.h>

#define NN 16384
#define EE 262144
#define GG 32
#define NPGC 512
#define NEG_SLOPE 0.2f

typedef __attribute__((ext_vector_type(8))) short bf16x8;
typedef __attribute__((ext_vector_type(4))) float f32x4;

// ---------------- build h = [aa_emb[ref]*aa_emb[alt[gid]] | feat] (bf16) ----------------
__global__ __launch_bounds__(320) void build_h_kernel(
    const float* __restrict__ feat, const float* __restrict__ aa_emb,
    const int* __restrict__ ref_aa, const int* __restrict__ alt_aa,
    const int* __restrict__ graph_id, __hip_bfloat16* __restrict__ h)
{
    int n = blockIdx.x, t = threadIdx.x;
    float v;
    if (t < 64) {
        int ra = ref_aa[n], ga = alt_aa[graph_id[n]];
        v = aa_emb[ra * 64 + t] * aa_emb[ga * 64 + t];
    } else {
        v = feat[(size_t)n * 256 + (t - 64)];
    }
    h[(size_t)n * 320 + t] = __float2bfloat16(v);
}

// ---------------- weight transpose+cast: out[c][k] = (c<C1 ? W[k][c] : R[k][c-C1]) ----------------
__global__ __launch_bounds__(256) void wtrans_kernel(
    const float* __restrict__ W, const float* __restrict__ R,
    int K, int C1, __hip_bfloat16* __restrict__ out)
{
    int k = blockIdx.x * 256 + threadIdx.x;
    int c = blockIdx.y;
    if (k >= K) return;
    float v = (c < C1) ? W[(size_t)k * C1 + c] : R[(size_t)k * C1 + (c - C1)];
    out[(size_t)c * K + k] = __float2bfloat16(v);
}

// ---------------- CSR build ----------------
__global__ __launch_bounds__(256) void deg_kernel(const int* __restrict__ dst, int* __restrict__ deg)
{
    int i = blockIdx.x * 256 + threadIdx.x;
    if (i < EE) atomicAdd(&deg[dst[i]], 1);
}

__global__ __launch_bounds__(256) void scan_kernel(const int* __restrict__ deg,
                                                   int* __restrict__ row, int* __restrict__ cursor)
{
    __shared__ int part[256];
    __shared__ int pref[257];
    int t = threadIdx.x, base = t * 64;
    int s = 0;
    for (int i = 0; i < 64; i++) s += deg[base + i];
    part[t] = s;
    __syncthreads();
    if (t == 0) {
        int a = 0;
        for (int i = 0; i < 256; i++) { pref[i] = a; a += part[i]; }
        pref[256] = a;
    }
    __syncthreads();
    int a = pref[t];
    for (int i = 0; i < 64; i++) {
        row[base + i] = a; cursor[base + i] = a;
        a += deg[base + i];
    }
    if (t == 0) row[NN] = pref[256];
}

__global__ __launch_bounds__(256) void scatter_kernel(const int* __restrict__ dst,
                                                      int* __restrict__ cursor, int* __restrict__ eid)
{
    int i = blockIdx.x * 256 + threadIdx.x;
    if (i < EE) {
        int p = atomicAdd(&cursor[dst[i]], 1);
        eid[p] = i;
    }
}

// ---------------- MFMA GEMM: C[M x NC] = A[M][K] @ Bt[NC][K]^T, split output ----------------
// 4 waves as 2x2, each wave owns (FR*16)x(FR*16); block tile BM=BN=32*FR; BK=64.
// LDS XOR-swizzle (T2): 16B slot index ^= (row&7) on both write and read.
template<int FR, int C1, int KTOT>
__global__ __launch_bounds__(256) void mfma_gemm_kernel(
    const __hip_bfloat16* __restrict__ A, const __hip_bfloat16* __restrict__ Bt,
    __hip_bfloat16* __restrict__ ftb, float* __restrict__ resf)
{
    constexpr int BM = 32 * FR;
    __shared__ short As[BM * 64];
    __shared__ short Bs[BM * 64];
    int t = threadIdx.x;
    int wid = t >> 6, lane = t & 63;
    int wr = wid >> 1, wc = wid & 1;
    int row0 = blockIdx.x * BM, col0 = blockIdx.y * BM;

    f32x4 acc[FR][FR];
#pragma unroll
    for (int m = 0; m < FR; m++)
#pragma unroll
        for (int n = 0; n < FR; n++) acc[m][n] = (f32x4){0.f, 0.f, 0.f, 0.f};

    for (int kk = 0; kk < KTOT; kk += 64) {
        __syncthreads();
#pragma unroll
        for (int c = t; c < BM * 8; c += 256) {
            int row = c >> 3, slot = c & 7;
            int sw = (slot ^ (row & 7)) * 8;
            bf16x8 va = *(const bf16x8*)(A + (size_t)(row0 + row) * KTOT + kk + slot * 8);
            *(bf16x8*)(&As[row * 64 + sw]) = va;
            bf16x8 vb = *(const bf16x8*)(Bt + (size_t)(col0 + row) * KTOT + kk + slot * 8);
            *(bf16x8*)(&Bs[row * 64 + sw]) = vb;
        }
        __syncthreads();
#pragma unroll
        for (int ks = 0; ks < 2; ks++) {
            int kslot = ks * 4 + (lane >> 4);
            bf16x8 a[FR], b[FR];
#pragma unroll
            for (int m = 0; m < FR; m++) {
                int row = wr * FR * 16 + m * 16 + (lane & 15);
                a[m] = *(const bf16x8*)(&As[row * 64 + ((kslot ^ (row & 7)) * 8)]);
            }
#pragma unroll
            for (int n = 0; n < FR; n++) {
                int col = wc * FR * 16 + n * 16 + (lane & 15);
                b[n] = *(const bf16x8*)(&Bs[col * 64 + ((kslot ^ (col & 7)) * 8)]);
            }
#pragma unroll
            for (int m = 0; m < FR; m++)
#pragma unroll
                for (int n = 0; n < FR; n++)
                    acc[m][n] = __builtin_amdgcn_mfma_f32_16x16x32_bf16(a[m], b[n], acc[m][n], 0, 0, 0);
        }
    }

#pragma unroll
    for (int m = 0; m < FR; m++)
#pragma unroll
        for (int n = 0; n < FR; n++) {
            int colg = col0 + wc * FR * 16 + n * 16 + (lane & 15);
            int rbase = row0 + wr * FR * 16 + m * 16 + (lane >> 4) * 4;
#pragma unroll
            for (int r = 0; r < 4; r++) {
                float v = acc[m][n][r];
                int rg = rbase + r;
                if (colg < C1) ftb[(size_t)rg * C1 + colg] = __float2bfloat16(v);
                else           resf[(size_t)rg * C1 + (colg - C1)] = v;
            }
        }
}

// ---------------- el/er per (node, head) from bf16 ft ----------------
template<int O>
__global__ __launch_bounds__(256) void elr_kernel(
    const __hip_bfloat16* __restrict__ ftb, int ldft,
    const float* __restrict__ al, const float* __restrict__ ar,
    float* __restrict__ el, float* __restrict__ er)
{
    int gid = blockIdx.x * 256 + threadIdx.x;
    int wv = gid >> 6, lane = gid & 63;
    int n = wv >> 1, hh = wv & 1;
    if (n >= NN) return;
    float sl = 0.f, sr = 0.f;
#pragma unroll
    for (int j = 0; j < O / 64; j++) {
        int o = j * 64 + lane;
        float f = __bfloat162float(ftb[(size_t)n * ldft + hh * O + o]);
        sl += f * al[hh * O + o];
        sr += f * ar[hh * O + o];
    }
#pragma unroll
    for (int d = 32; d; d >>= 1) { sl += __shfl_xor(sl, d); sr += __shfl_xor(sr, d); }
    if (lane == 0) { el[n * 2 + hh] = sl; er[n * 2 + hh] = sr; }
}

// ---------------- edge softmax weights ----------------
template<bool FIRST>
__global__ __launch_bounds__(256) void alpha_kernel(
    const int* __restrict__ row, const int* __restrict__ eid,
    const int* __restrict__ src, int* __restrict__ srcs,
    const float* __restrict__ el, const float* __restrict__ er,
    float* __restrict__ alpha, float* __restrict__ inv)
{
    int gid = blockIdx.x * 256 + threadIdx.x;
    int n = gid >> 6, lane = gid & 63;
    if (n >= NN) return;
    int e0 = row[n], e1 = row[n + 1];
    float er0v = er[n * 2 + 0], er1v = er[n * 2 + 1];

    float m0 = -1e30f, m1 = -1e30f;
    for (int p = e0 + lane; p < e1; p += 64) {
        int s;
        if (FIRST) { s = src[eid[p]]; srcs[p] = s; }
        else       { s = srcs[p]; }
        float v0 = el[s * 2 + 0] + er0v; v0 = v0 > 0.f ? v0 : NEG_SLOPE * v0;
        float v1 = el[s * 2 + 1] + er1v; v1 = v1 > 0.f ? v1 : NEG_SLOPE * v1;
        m0 = fmaxf(m0, v0); m1 = fmaxf(m1, v1);
    }
#pragma unroll
    for (int d = 32; d; d >>= 1) {
        m0 = fmaxf(m0, __shfl_xor(m0, d));
        m1 = fmaxf(m1, __shfl_xor(m1, d));
    }
    float s0 = 0.f, s1 = 0.f;
    for (int p = e0 + lane; p < e1; p += 64) {
        int s = srcs[p];
        float v0 = el[s * 2 + 0] + er0v; v0 = v0 > 0.f ? v0 : NEG_SLOPE * v0;
        float v1 = el[s * 2 + 1] + er1v; v1 = v1 > 0.f ? v1 : NEG_SLOPE * v1;
        float w0 = __expf(v0 - m0), w1 = __expf(v1 - m1);
        alpha[p * 2 + 0] = w0; alpha[p * 2 + 1] = w1;
        s0 += w0; s1 += w1;
    }
#pragma unroll
    for (int d = 32; d; d >>= 1) { s0 += __shfl_xor(s0, d); s1 += __shfl_xor(s1, d); }
    if (lane == 0) {
        inv[n * 2 + 0] = s0 > 0.f ? 1.f / s0 : 0.f;
        inv[n * 2 + 1] = s1 > 0.f ? 1.f / s1 : 0.f;
    }
}

// ---------------- layer0 aggregation -> h1 (bf16) ----------------
__global__ __launch_bounds__(128) void agg0_kernel(
    const __hip_bfloat16* __restrict__ ftb0, const float* __restrict__ resf0,
    const int* __restrict__ row, const int* __restrict__ srcs,
    const float* __restrict__ alpha, const float* __restrict__ inv,
    const float* __restrict__ b0, __hip_bfloat16* __restrict__ h1)
{
    __shared__ int s_src[128];
    __shared__ float s_a[256];
    int n = blockIdx.x, t = threadIdx.x;
    int hh = t >> 6;
    int e0 = row[n], e1 = row[n + 1];
    float acc = 0.f;
    for (int base = e0; base < e1; base += 128) {
        int c = min(128, e1 - base);
        __syncthreads();
        if (t < c) s_src[t] = srcs[base + t];
        if (t < 2 * c) s_a[t] = alpha[base * 2 + t];
        __syncthreads();
        int i = 0;
        for (; i + 4 <= c; i += 4) {
            int n0 = s_src[i], n1 = s_src[i + 1], n2 = s_src[i + 2], n3 = s_src[i + 3];
            float a0 = s_a[2 * i + hh],       a1 = s_a[2 * (i + 1) + hh];
            float a2 = s_a[2 * (i + 2) + hh], a3 = s_a[2 * (i + 3) + hh];
            float f0 = __bfloat162float(ftb0[(size_t)n0 * 128 + t]);
            float f1 = __bfloat162float(ftb0[(size_t)n1 * 128 + t]);
            float f2 = __bfloat162float(ftb0[(size_t)n2 * 128 + t]);
            float f3 = __bfloat162float(ftb0[(size_t)n3 * 128 + t]);
            acc += a0 * f0; acc += a1 * f1; acc += a2 * f2; acc += a3 * f3;
        }
        for (; i < c; i++) {
            acc += s_a[2 * i + hh] * __bfloat162float(ftb0[(size_t)s_src[i] * 128 + t]);
        }
    }
    float r = acc * inv[n * 2 + hh] + resf0[(size_t)n * 128 + t] + b0[t];
    r = r > 0.f ? r : (__expf(r) - 1.f);
    h1[(size_t)n * 128 + t] = __float2bfloat16(r);
}

// ---------------- layer1 aggregation + head-mean + ELU: h2[N,256] ----------------
__global__ __launch_bounds__(512) void agg1_kernel(
    const __hip_bfloat16* __restrict__ ftb1, const float* __restrict__ resf1,
    const int* __restrict__ row, const int* __restrict__ srcs,
    const float* __restrict__ alpha, const float* __restrict__ inv,
    const float* __restrict__ b1, float* __restrict__ h2)
{
    __shared__ int s_src[256];
    __shared__ float s_a[512];
    __shared__ float tmp[256];
    int n = blockIdx.x, t = threadIdx.x;
    int hh = t >> 8, o = t & 255;
    int e0 = row[n], e1 = row[n + 1];
    float acc = 0.f;
    for (int base = e0; base < e1; base += 256) {
        int c = min(256, e1 - base);
        __syncthreads();
        if (t < c) s_src[t] = srcs[base + t];
        if (t < 2 * c) s_a[t] = alpha[base * 2 + t];
        __syncthreads();
        int i = 0;
        for (; i + 4 <= c; i += 4) {
            int n0 = s_src[i], n1 = s_src[i + 1], n2 = s_src[i + 2], n3 = s_src[i + 3];
            float a0 = s_a[2 * i + hh],       a1 = s_a[2 * (i + 1) + hh];
            float a2 = s_a[2 * (i + 2) + hh], a3 = s_a[2 * (i + 3) + hh];
            float f0 = __bfloat162float(ftb1[(size_t)n0 * 512 + hh * 256 + o]);
            float f1 = __bfloat162float(ftb1[(size_t)n1 * 512 + hh * 256 + o]);
            float f2 = __bfloat162float(ftb1[(size_t)n2 * 512 + hh * 256 + o]);
            float f3 = __bfloat162float(ftb1[(size_t)n3 * 512 + hh * 256 + o]);
            acc += a0 * f0; acc += a1 * f1; acc += a2 * f2; acc += a3 * f3;
        }
        for (; i < c; i++) {
            acc += s_a[2 * i + hh] * __bfloat162float(ftb1[(size_t)s_src[i] * 512 + hh * 256 + o]);
        }
    }
    float r = acc * inv[n * 2 + hh] + resf1[(size_t)n * 512 + hh * 256 + o] + b1[hh * 256 + o];
    if (hh == 1) tmp[o] = r;
    __syncthreads();
    if (hh == 0) {
        float v = 0.5f * (r + tmp[o]);
        h2[(size_t)n * 256 + o] = v > 0.f ? v : (__expf(v) - 1.f);
    }
}

// ---------------- per-graph mean readout + 3-layer MLP ----------------
__global__ __launch_bounds__(256) void readout_mlp_kernel(
    const float* __restrict__ h2,
    const float* __restrict__ mW0, const float* __restrict__ mb0,
    const float* __restrict__ mW1, const float* __restrict__ mb1,
    const float* __restrict__ mW2, const float* __restrict__ mb2,
    float* __restrict__ out)
{
    __shared__ float hg[256];
    __shared__ float x1[128];
    __shared__ float x2[64];
    int g = blockIdx.x, t = threadIdx.x;
    float s = 0.f;
    for (int i = 0; i < NPGC; i++) s += h2[(size_t)(g * NPGC + i) * 256 + t];
    hg[t] = s * (1.f / (float)NPGC);
    __syncthreads();
    if (t < 128) {
        float a = mb0[t];
        for (int k = 0; k < 256; k++) a += hg[k] * mW0[k * 128 + t];
        x1[t] = fmaxf(a, 0.f);
    }
    __syncthreads();
    if (t < 64) {
        float a = mb1[t];
        for (int k = 0; k < 128; k++) a += x1[k] * mW1[k * 64 + t];
        x2[t] = fmaxf(a, 0.f);
    }
    __syncthreads();
    if (t < 2) {
        float a = mb2[t];
        for (int k = 0; k < 64; k++) a += x2[k] * mW2[k * 2 + t];
        out[g * 2 + t] = a;
    }
}

extern "C" void kernel_launch(void* const* d_in, const int* in_sizes, int n_in,
                              void* d_out, int out_size, void* d_ws, size_t ws_size,
                              hipStream_t stream)
{
    const float* feat   = (const float*)d_in[0];
    const float* aa_emb = (const float*)d_in[1];
    const float* W0     = (const float*)d_in[2];
    const float* al0    = (const float*)d_in[3];
    const float* ar0    = (const float*)d_in[4];
    const float* res0   = (const float*)d_in[5];
    const float* b0     = (const float*)d_in[6];
    const float* W1     = (const float*)d_in[7];
    const float* al1    = (const float*)d_in[8];
    const float* ar1    = (const float*)d_in[9];
    const float* res1   = (const float*)d_in[10];
    const float* b1     = (const float*)d_in[11];
    const float* mW0    = (const float*)d_in[12];
    const float* mb0    = (const float*)d_in[13];
    const float* mW1    = (const float*)d_in[14];
    const float* mb1    = (const float*)d_in[15];
    const float* mW2    = (const float*)d_in[16];
    const float* mb2    = (const float*)d_in[17];
    const int* ref_aa   = (const int*)d_in[18];
    const int* alt_aa   = (const int*)d_in[19];
    const int* src      = (const int*)d_in[20];
    const int* dst      = (const int*)d_in[21];
    const int* graph_id = (const int*)d_in[22];
    float* out = (float*)d_out;

    size_t off = 0;
    auto alloc = [&](size_t bytes) -> void* {
        void* p = (char*)d_ws + off;
        off += (bytes + 255) & ~(size_t)255;
        return p;
    };
    __hip_bfloat16* h    = (__hip_bfloat16*)alloc((size_t)NN * 320 * 2);
    __hip_bfloat16* wt0  = (__hip_bfloat16*)alloc((size_t)256 * 320 * 2);
    __hip_bfloat16* wt1  = (__hip_bfloat16*)alloc((size_t)1024 * 128 * 2);
    __hip_bfloat16* ftb0 = (__hip_bfloat16*)alloc((size_t)NN * 128 * 2);
    float* resf0  = (float*)alloc((size_t)NN * 128 * 4);
    __hip_bfloat16* h1b  = (__hip_bfloat16*)alloc((size_t)NN * 128 * 2);
    __hip_bfloat16* ftb1 = (__hip_bfloat16*)alloc((size_t)NN * 512 * 2);
    float* resf1  = (float*)alloc((size_t)NN * 512 * 4);
    float* h2     = (float*)alloc((size_t)NN * 256 * 4);
    float* el0    = (float*)alloc((size_t)NN * 2 * 4);
    float* er0    = (float*)alloc((size_t)NN * 2 * 4);
    float* el1    = (float*)alloc((size_t)NN * 2 * 4);
    float* er1    = (float*)alloc((size_t)NN * 2 * 4);
    float* inv0   = (float*)alloc((size_t)NN * 2 * 4);
    float* inv1   = (float*)alloc((size_t)NN * 2 * 4);
    int* deg      = (int*)alloc((size_t)NN * 4);
    int* row      = (int*)alloc((size_t)(NN + 1) * 4);
    int* cursor   = (int*)alloc((size_t)NN * 4);
    int* eid      = (int*)alloc((size_t)EE * 4);
    int* srcs     = (int*)alloc((size_t)EE * 4);
    float* alpha0 = (float*)alloc((size_t)EE * 2 * 4);
    float* alpha1 = (float*)alloc((size_t)EE * 2 * 4);

    (void)in_sizes; (void)n_in; (void)out_size; (void)ws_size;

    hipMemsetAsync(deg, 0, (size_t)NN * 4, stream);
    build_h_kernel<<<NN, 320, 0, stream>>>(feat, aa_emb, ref_aa, alt_aa, graph_id, h);
    wtrans_kernel<<<dim3(2, 256), 256, 0, stream>>>(W0, res0, 320, 128, wt0);
    wtrans_kernel<<<dim3(1, 1024), 256, 0, stream>>>(W1, res1, 128, 512, wt1);
    deg_kernel<<<EE / 256, 256, 0, stream>>>(dst, deg);
    scan_kernel<<<1, 256, 0, stream>>>(deg, row, cursor);
    scatter_kernel<<<EE / 256, 256, 0, stream>>>(dst, cursor, eid);

    // layer 0: [ftb0 | resf0] = h @ [W0 | res0]   (MFMA, 64x64 tiles)
    mfma_gemm_kernel<2, 128, 320><<<dim3(256, 4), 256, 0, stream>>>(h, wt0, ftb0, resf0);
    elr_kernel<64><<<(NN * 2 * 64) / 256, 256, 0, stream>>>(ftb0, 128, al0, ar0, el0, er0);
    alpha_kernel<true><<<NN / 4, 256, 0, stream>>>(row, eid, src, srcs, el0, er0, alpha0, inv0);
    agg0_kernel<<<NN, 128, 0, stream>>>(ftb0, resf0, row, srcs, alpha0, inv0, b0, h1b);

    // layer 1: [ftb1 | resf1] = h1 @ [W1 | res1]  (MFMA, 128x128 tiles)
    mfma_gemm_kernel<4, 512, 128><<<dim3(128, 8), 256, 0, stream>>>(h1b, wt1, ftb1, resf1);
    elr_kernel<256><<<(NN * 2 * 64) / 256, 256, 0, stream>>>(ftb1, 512, al1, ar1, el1, er1);
    alpha_kernel<false><<<NN / 4, 256, 0, stream>>>(row, eid, src, srcs, el1, er1, alpha1, inv1);
    agg1_kernel<<<NN, 512, 0, stream>>>(ftb1, resf1, row, srcs, alpha1, inv1, b1, h2);

    // readout + MLP
    readout_mlp_kernel<<<GG, 256, 0, stream>>>(h2, mW0, mb0, mW1, mb1, mW2, mb2, out);
}

// Round 5
// 188.442 us; speedup vs baseline: 2.9298x; 1.2081x over previous
//
#include <hip/hip_runtime.h>
#include <hip/hip_bf16.h>

#define NN 16384
#define EE 262144
#define GG 32
#define NPGC 512
#define NEG_SLOPE 0.2f

typedef __attribute__((ext_vector_type(8))) short bf16x8;
typedef __attribute__((ext_vector_type(4))) float f32x4;

__device__ __forceinline__ float b2f(short s) {
    union { float f; unsigned u; } c;
    c.u = ((unsigned)(unsigned short)s) << 16;
    return c.f;
}

__device__ __forceinline__ short f2b(float f) {
    __hip_bfloat16 b = __float2bfloat16(f);
    short r;
    __builtin_memcpy(&r, &b, 2);
    return r;
}

// ---------------- build h = [aa_emb[ref]*aa_emb[alt[gid]] | feat] (bf16) ----------------
__global__ __launch_bounds__(320) void build_h_kernel(
    const float* __restrict__ feat, const float* __restrict__ aa_emb,
    const int* __restrict__ ref_aa, const int* __restrict__ alt_aa,
    const int* __restrict__ graph_id, __hip_bfloat16* __restrict__ h)
{
    int n = blockIdx.x, t = threadIdx.x;
    float v;
    if (t < 64) {
        int ra = ref_aa[n], ga = alt_aa[graph_id[n]];
        v = aa_emb[ra * 64 + t] * aa_emb[ga * 64 + t];
    } else {
        v = feat[(size_t)n * 256 + (t - 64)];
    }
    h[(size_t)n * 320 + t] = __float2bfloat16(v);
}

// ---------------- weight transpose+cast ----------------
__global__ __launch_bounds__(256) void wtrans_kernel(
    const float* __restrict__ W, const float* __restrict__ R,
    int K, int C1, __hip_bfloat16* __restrict__ out)
{
    int k = blockIdx.x * 256 + threadIdx.x;
    int c = blockIdx.y;
    if (k >= K) return;
    float v = (c < C1) ? W[(size_t)k * C1 + c] : R[(size_t)k * C1 + (c - C1)];
    out[(size_t)c * K + k] = __float2bfloat16(v);
}

// ---------------- CSR build ----------------
__global__ __launch_bounds__(256) void deg_kernel(const int* __restrict__ dst, int* __restrict__ deg)
{
    int i = blockIdx.x * 256 + threadIdx.x;
    if (i < EE) atomicAdd(&deg[dst[i]], 1);
}

__global__ __launch_bounds__(256) void scan_kernel(const int* __restrict__ deg,
                                                   int* __restrict__ row, int* __restrict__ cursor)
{
    __shared__ int part[256];
    __shared__ int pref[257];
    int t = threadIdx.x, base = t * 64;
    int s = 0;
    for (int i = 0; i < 64; i++) s += deg[base + i];
    part[t] = s;
    __syncthreads();
    if (t == 0) {
        int a = 0;
        for (int i = 0; i < 256; i++) { pref[i] = a; a += part[i]; }
        pref[256] = a;
    }
    __syncthreads();
    int a = pref[t];
    for (int i = 0; i < 64; i++) {
        row[base + i] = a; cursor[base + i] = a;
        a += deg[base + i];
    }
    if (t == 0) row[NN] = pref[256];
}

__global__ __launch_bounds__(256) void scatter_kernel(const int* __restrict__ dst,
                                                      int* __restrict__ cursor, int* __restrict__ eid)
{
    int i = blockIdx.x * 256 + threadIdx.x;
    if (i < EE) {
        int p = atomicAdd(&cursor[dst[i]], 1);
        eid[p] = i;
    }
}

// ---------------- MFMA GEMM (as R2) ----------------
template<int FR, int C1, int KTOT>
__global__ __launch_bounds__(256) void mfma_gemm_kernel(
    const __hip_bfloat16* __restrict__ A, const __hip_bfloat16* __restrict__ Bt,
    __hip_bfloat16* __restrict__ ftb, float* __restrict__ resf)
{
    constexpr int BM = 32 * FR;
    __shared__ short As[BM * 64];
    __shared__ short Bs[BM * 64];
    int t = threadIdx.x;
    int wid = t >> 6, lane = t & 63;
    int wr = wid >> 1, wc = wid & 1;
    int row0 = blockIdx.x * BM, col0 = blockIdx.y * BM;

    f32x4 acc[FR][FR];
#pragma unroll
    for (int m = 0; m < FR; m++)
#pragma unroll
        for (int n = 0; n < FR; n++) acc[m][n] = (f32x4){0.f, 0.f, 0.f, 0.f};

    for (int kk = 0; kk < KTOT; kk += 64) {
        __syncthreads();
#pragma unroll
        for (int c = t; c < BM * 8; c += 256) {
            int row = c >> 3, slot = c & 7;
            int sw = (slot ^ (row & 7)) * 8;
            bf16x8 va = *(const bf16x8*)(A + (size_t)(row0 + row) * KTOT + kk + slot * 8);
            *(bf16x8*)(&As[row * 64 + sw]) = va;
            bf16x8 vb = *(const bf16x8*)(Bt + (size_t)(col0 + row) * KTOT + kk + slot * 8);
            *(bf16x8*)(&Bs[row * 64 + sw]) = vb;
        }
        __syncthreads();
#pragma unroll
        for (int ks = 0; ks < 2; ks++) {
            int kslot = ks * 4 + (lane >> 4);
            bf16x8 a[FR], b[FR];
#pragma unroll
            for (int m = 0; m < FR; m++) {
                int row = wr * FR * 16 + m * 16 + (lane & 15);
                a[m] = *(const bf16x8*)(&As[row * 64 + ((kslot ^ (row & 7)) * 8)]);
            }
#pragma unroll
            for (int n = 0; n < FR; n++) {
                int col = wc * FR * 16 + n * 16 + (lane & 15);
                b[n] = *(const bf16x8*)(&Bs[col * 64 + ((kslot ^ (col & 7)) * 8)]);
            }
#pragma unroll
            for (int m = 0; m < FR; m++)
#pragma unroll
                for (int n = 0; n < FR; n++)
                    acc[m][n] = __builtin_amdgcn_mfma_f32_16x16x32_bf16(a[m], b[n], acc[m][n], 0, 0, 0);
        }
    }

#pragma unroll
    for (int m = 0; m < FR; m++)
#pragma unroll
        for (int n = 0; n < FR; n++) {
            int colg = col0 + wc * FR * 16 + n * 16 + (lane & 15);
            int rbase = row0 + wr * FR * 16 + m * 16 + (lane >> 4) * 4;
#pragma unroll
            for (int r = 0; r < 4; r++) {
                float v = acc[m][n][r];
                int rg = rbase + r;
                if (colg < C1) ftb[(size_t)rg * C1 + colg] = __float2bfloat16(v);
                else           resf[(size_t)rg * C1 + (colg - C1)] = v;
            }
        }
}

// ---------------- layer0 el/er (scalar, O=64) ----------------
__global__ __launch_bounds__(256) void elr0_kernel(
    const __hip_bfloat16* __restrict__ ftb,
    const float* __restrict__ al, const float* __restrict__ ar,
    float* __restrict__ el, float* __restrict__ er)
{
    int gid = blockIdx.x * 256 + threadIdx.x;
    int wv = gid >> 6, lane = gid & 63;
    int n = wv >> 1, hh = wv & 1;
    if (n >= NN) return;
    float f = b2f(((const short*)ftb)[(size_t)n * 128 + hh * 64 + lane]);
    float sl = f * al[hh * 64 + lane];
    float sr = f * ar[hh * 64 + lane];
#pragma unroll
    for (int d = 32; d; d >>= 1) { sl += __shfl_xor(sl, d); sr += __shfl_xor(sr, d); }
    if (lane == 0) { el[n * 2 + hh] = sl; er[n * 2 + hh] = sr; }
}

// ---------------- layer1 el/er: one wave per node, vectorized ----------------
__global__ __launch_bounds__(256) void elr1_kernel(
    const __hip_bfloat16* __restrict__ ftb,
    const float* __restrict__ al, const float* __restrict__ ar,
    float* __restrict__ el, float* __restrict__ er)
{
    int wv = (blockIdx.x * 256 + threadIdx.x) >> 6;
    int lane = threadIdx.x & 63;
    if (wv >= NN) return;
    int n = wv, hh = lane >> 5, dim = lane * 8;
    bf16x8 v = *(const bf16x8*)((const short*)ftb + (size_t)n * 512 + dim);
    float sl = 0.f, sr = 0.f;
#pragma unroll
    for (int j = 0; j < 8; j++) {
        float f = b2f(v[j]);
        sl += f * al[dim + j];
        sr += f * ar[dim + j];
    }
#pragma unroll
    for (int d = 16; d; d >>= 1) { sl += __shfl_xor(sl, d); sr += __shfl_xor(sr, d); }
    if ((lane & 31) == 0) { el[n * 2 + hh] = sl; er[n * 2 + hh] = sr; }
}

// ---------------- edge softmax weights ----------------
template<bool FIRST>
__global__ __launch_bounds__(256) void alpha_kernel(
    const int* __restrict__ row, const int* __restrict__ eid,
    const int* __restrict__ src, int* __restrict__ srcs,
    const float* __restrict__ el, const float* __restrict__ er,
    float* __restrict__ alpha, float* __restrict__ inv)
{
    int gid = blockIdx.x * 256 + threadIdx.x;
    int n = gid >> 6, lane = gid & 63;
    if (n >= NN) return;
    int e0 = row[n], e1 = row[n + 1];
    float er0v = er[n * 2 + 0], er1v = er[n * 2 + 1];

    float m0 = -1e30f, m1 = -1e30f;
    for (int p = e0 + lane; p < e1; p += 64) {
        int s;
        if (FIRST) { s = src[eid[p]]; srcs[p] = s; }
        else       { s = srcs[p]; }
        float v0 = el[s * 2 + 0] + er0v; v0 = v0 > 0.f ? v0 : NEG_SLOPE * v0;
        float v1 = el[s * 2 + 1] + er1v; v1 = v1 > 0.f ? v1 : NEG_SLOPE * v1;
        m0 = fmaxf(m0, v0); m1 = fmaxf(m1, v1);
    }
#pragma unroll
    for (int d = 32; d; d >>= 1) {
        m0 = fmaxf(m0, __shfl_xor(m0, d));
        m1 = fmaxf(m1, __shfl_xor(m1, d));
    }
    float s0 = 0.f, s1 = 0.f;
    for (int p = e0 + lane; p < e1; p += 64) {
        int s = srcs[p];
        float v0 = el[s * 2 + 0] + er0v; v0 = v0 > 0.f ? v0 : NEG_SLOPE * v0;
        float v1 = el[s * 2 + 1] + er1v; v1 = v1 > 0.f ? v1 : NEG_SLOPE * v1;
        float w0 = __expf(v0 - m0), w1 = __expf(v1 - m1);
        alpha[p * 2 + 0] = w0; alpha[p * 2 + 1] = w1;
        s0 += w0; s1 += w1;
    }
#pragma unroll
    for (int d = 32; d; d >>= 1) { s0 += __shfl_xor(s0, d); s1 += __shfl_xor(s1, d); }
    if (lane == 0) {
        inv[n * 2 + 0] = s0 > 0.f ? 1.f / s0 : 0.f;
        inv[n * 2 + 1] = s1 > 0.f ? 1.f / s1 : 0.f;
    }
}

// ---------------- layer0 aggregation: wave per node, 4 edge-groups x 16 chunks ----------------
__global__ __launch_bounds__(256) void agg0_kernel(
    const __hip_bfloat16* __restrict__ ftb0, const float* __restrict__ resf0,
    const int* __restrict__ row, const int* __restrict__ srcs,
    const float* __restrict__ alpha, const float* __restrict__ inv,
    const float* __restrict__ b0, __hip_bfloat16* __restrict__ h1)
{
    int wv = (blockIdx.x * 256 + threadIdx.x) >> 6;
    int lane = threadIdx.x & 63;
    if (wv >= NN) return;
    int n = wv;
    int eo = lane >> 4, vo = lane & 15;
    int hh = vo >> 3, dim = vo * 8;
    int e0 = row[n], e1 = row[n + 1];
    float acc[8] = {0.f, 0.f, 0.f, 0.f, 0.f, 0.f, 0.f, 0.f};
    for (int p = e0 + eo; p < e1; p += 4) {
        int s = srcs[p];
        float a = alpha[2 * p + hh];
        bf16x8 v = *(const bf16x8*)((const short*)ftb0 + (size_t)s * 128 + dim);
#pragma unroll
        for (int j = 0; j < 8; j++) acc[j] += a * b2f(v[j]);
    }
#pragma unroll
    for (int j = 0; j < 8; j++) acc[j] += __shfl_xor(acc[j], 16);
#pragma unroll
    for (int j = 0; j < 8; j++) acc[j] += __shfl_xor(acc[j], 32);
    if (eo == 0) {
        float invv = inv[n * 2 + hh];
        bf16x8 o;
#pragma unroll
        for (int j = 0; j < 8; j++) {
            float r = acc[j] * invv + resf0[(size_t)n * 128 + dim + j] + b0[dim + j];
            r = r > 0.f ? r : (__expf(r) - 1.f);
            o[j] = f2b(r);
        }
        *(bf16x8*)((short*)h1 + (size_t)n * 128 + dim) = o;
    }
}

// ---------------- layer1 aggregation: wave per node, lane owns 8 dims ----------------
__global__ __launch_bounds__(256) void agg1_kernel(
    const __hip_bfloat16* __restrict__ ftb1, const float* __restrict__ resf1,
    const int* __restrict__ row, const int* __restrict__ srcs,
    const float* __restrict__ alpha, const float* __restrict__ inv,
    const float* __restrict__ b1, float* __restrict__ h2)
{
    int wv = (blockIdx.x * 256 + threadIdx.x) >> 6;
    int lane = threadIdx.x & 63;
    if (wv >= NN) return;
    int n = wv;
    int hh = lane >> 5, dim = lane * 8;
    int e0 = row[n], e1 = row[n + 1];
    float acc[8] = {0.f, 0.f, 0.f, 0.f, 0.f, 0.f, 0.f, 0.f};
    int p = e0;
    for (; p + 4 <= e1; p += 4) {
        int s0 = srcs[p], s1 = srcs[p + 1], s2 = srcs[p + 2], s3 = srcs[p + 3];
        float a0 = alpha[2 * p + hh],     a1 = alpha[2 * p + 2 + hh];
        float a2 = alpha[2 * p + 4 + hh], a3 = alpha[2 * p + 6 + hh];
        bf16x8 v0 = *(const bf16x8*)((const short*)ftb1 + (size_t)s0 * 512 + dim);
        bf16x8 v1 = *(const bf16x8*)((const short*)ftb1 + (size_t)s1 * 512 + dim);
        bf16x8 v2 = *(const bf16x8*)((const short*)ftb1 + (size_t)s2 * 512 + dim);
        bf16x8 v3 = *(const bf16x8*)((const short*)ftb1 + (size_t)s3 * 512 + dim);
#pragma unroll
        for (int j = 0; j < 8; j++) {
            acc[j] += a0 * b2f(v0[j]) + a1 * b2f(v1[j]) + a2 * b2f(v2[j]) + a3 * b2f(v3[j]);
        }
    }
    for (; p < e1; p++) {
        int s = srcs[p];
        float a = alpha[2 * p + hh];
        bf16x8 v = *(const bf16x8*)((const short*)ftb1 + (size_t)s * 512 + dim);
#pragma unroll
        for (int j = 0; j < 8; j++) acc[j] += a * b2f(v[j]);
    }
    float invv = inv[n * 2 + hh];
    float r[8];
#pragma unroll
    for (int j = 0; j < 8; j++)
        r[j] = acc[j] * invv + resf1[(size_t)n * 512 + dim + j] + b1[dim + j];
    float v[8];
#pragma unroll
    for (int j = 0; j < 8; j++) {
        float o = __shfl_xor(r[j], 32);
        v[j] = 0.5f * (r[j] + o);
    }
    if (lane < 32) {
#pragma unroll
        for (int j = 0; j < 8; j++) {
            float x = v[j];
            v[j] = x > 0.f ? x : (__expf(x) - 1.f);
        }
        float* outp = h2 + (size_t)n * 256 + lane * 8;
        *(f32x4*)outp = (f32x4){v[0], v[1], v[2], v[3]};
        *(f32x4*)(outp + 4) = (f32x4){v[4], v[5], v[6], v[7]};
    }
}

// ---------------- readout stage 1: partial sums over 32-node chunks ----------------
__global__ __launch_bounds__(256) void readout1_kernel(
    const float* __restrict__ h2, float* __restrict__ part)
{
    int blk = blockIdx.x;           // g*16 + c
    int g = blk >> 4, c = blk & 15;
    int t = threadIdx.x;
    float s = 0.f;
    int base = g * NPGC + c * 32;
    for (int i = 0; i < 32; i++) s += h2[(size_t)(base + i) * 256 + t];
    part[(size_t)blk * 256 + t] = s;
}

// ---------------- readout stage 2: combine + MLP ----------------
__global__ __launch_bounds__(256) void readout2_kernel(
    const float* __restrict__ part,
    const float* __restrict__ mW0, const float* __restrict__ mb0,
    const float* __restrict__ mW1, const float* __restrict__ mb1,
    const float* __restrict__ mW2, const float* __restrict__ mb2,
    float* __restrict__ out)
{
    __shared__ float hg[256];
    __shared__ float x1[128];
    __shared__ float x2[64];
    int g = blockIdx.x, t = threadIdx.x;
    float s = 0.f;
    for (int c = 0; c < 16; c++) s += part[(size_t)(g * 16 + c) * 256 + t];
    hg[t] = s * (1.f / (float)NPGC);
    __syncthreads();
    if (t < 128) {
        float a = mb0[t];
        for (int k = 0; k < 256; k++) a += hg[k] * mW0[k * 128 + t];
        x1[t] = fmaxf(a, 0.f);
    }
    __syncthreads();
    if (t < 64) {
        float a = mb1[t];
        for (int k = 0; k < 128; k++) a += x1[k] * mW1[k * 64 + t];
        x2[t] = fmaxf(a, 0.f);
    }
    __syncthreads();
    if (t < 2) {
        float a = mb2[t];
        for (int k = 0; k < 64; k++) a += x2[k] * mW2[k * 2 + t];
        out[g * 2 + t] = a;
    }
}

extern "C" void kernel_launch(void* const* d_in, const int* in_sizes, int n_in,
                              void* d_out, int out_size, void* d_ws, size_t ws_size,
                              hipStream_t stream)
{
    const float* feat   = (const float*)d_in[0];
    const float* aa_emb = (const float*)d_in[1];
    const float* W0     = (const float*)d_in[2];
    const float* al0    = (const float*)d_in[3];
    const float* ar0    = (const float*)d_in[4];
    const float* res0   = (const float*)d_in[5];
    const float* b0     = (const float*)d_in[6];
    const float* W1     = (const float*)d_in[7];
    const float* al1    = (const float*)d_in[8];
    const float* ar1    = (const float*)d_in[9];
    const float* res1   = (const float*)d_in[10];
    const float* b1     = (const float*)d_in[11];
    const float* mW0    = (const float*)d_in[12];
    const float* mb0    = (const float*)d_in[13];
    const float* mW1    = (const float*)d_in[14];
    const float* mb1    = (const float*)d_in[15];
    const float* mW2    = (const float*)d_in[16];
    const float* mb2    = (const float*)d_in[17];
    const int* ref_aa   = (const int*)d_in[18];
    const int* alt_aa   = (const int*)d_in[19];
    const int* src      = (const int*)d_in[20];
    const int* dst      = (const int*)d_in[21];
    const int* graph_id = (const int*)d_in[22];
    float* out = (float*)d_out;

    size_t off = 0;
    auto alloc = [&](size_t bytes) -> void* {
        void* p = (char*)d_ws + off;
        off += (bytes + 255) & ~(size_t)255;
        return p;
    };
    __hip_bfloat16* h    = (__hip_bfloat16*)alloc((size_t)NN * 320 * 2);
    __hip_bfloat16* wt0  = (__hip_bfloat16*)alloc((size_t)256 * 320 * 2);
    __hip_bfloat16* wt1  = (__hip_bfloat16*)alloc((size_t)1024 * 128 * 2);
    __hip_bfloat16* ftb0 = (__hip_bfloat16*)alloc((size_t)NN * 128 * 2);
    float* resf0  = (float*)alloc((size_t)NN * 128 * 4);
    __hip_bfloat16* h1b  = (__hip_bfloat16*)alloc((size_t)NN * 128 * 2);
    __hip_bfloat16* ftb1 = (__hip_bfloat16*)alloc((size_t)NN * 512 * 2);
    float* resf1  = (float*)alloc((size_t)NN * 512 * 4);
    float* h2     = (float*)alloc((size_t)NN * 256 * 4);
    float* el0    = (float*)alloc((size_t)NN * 2 * 4);
    float* er0    = (float*)alloc((size_t)NN * 2 * 4);
    float* el1    = (float*)alloc((size_t)NN * 2 * 4);
    float* er1    = (float*)alloc((size_t)NN * 2 * 4);
    float* inv0   = (float*)alloc((size_t)NN * 2 * 4);
    float* inv1   = (float*)alloc((size_t)NN * 2 * 4);
    int* deg      = (int*)alloc((size_t)NN * 4);
    int* row      = (int*)alloc((size_t)(NN + 1) * 4);
    int* cursor   = (int*)alloc((size_t)NN * 4);
    int* eid      = (int*)alloc((size_t)EE * 4);
    int* srcs     = (int*)alloc((size_t)EE * 4);
    float* alpha0 = (float*)alloc((size_t)EE * 2 * 4);
    float* alpha1 = (float*)alloc((size_t)EE * 2 * 4);
    float* part   = (float*)alloc((size_t)GG * 16 * 256 * 4);

    (void)in_sizes; (void)n_in; (void)out_size; (void)ws_size;

    (void)hipMemsetAsync(deg, 0, (size_t)NN * 4, stream);
    build_h_kernel<<<NN, 320, 0, stream>>>(feat, aa_emb, ref_aa, alt_aa, graph_id, h);
    wtrans_kernel<<<dim3(2, 256), 256, 0, stream>>>(W0, res0, 320, 128, wt0);
    wtrans_kernel<<<dim3(1, 1024), 256, 0, stream>>>(W1, res1, 128, 512, wt1);
    deg_kernel<<<EE / 256, 256, 0, stream>>>(dst, deg);
    scan_kernel<<<1, 256, 0, stream>>>(deg, row, cursor);
    scatter_kernel<<<EE / 256, 256, 0, stream>>>(dst, cursor, eid);

    // layer 0
    mfma_gemm_kernel<2, 128, 320><<<dim3(256, 4), 256, 0, stream>>>(h, wt0, ftb0, resf0);
    elr0_kernel<<<(NN * 2 * 64) / 256, 256, 0, stream>>>(ftb0, al0, ar0, el0, er0);
    alpha_kernel<true><<<NN / 4, 256, 0, stream>>>(row, eid, src, srcs, el0, er0, alpha0, inv0);
    agg0_kernel<<<NN / 4, 256, 0, stream>>>(ftb0, resf0, row, srcs, alpha0, inv0, b0, h1b);

    // layer 1
    mfma_gemm_kernel<4, 512, 128><<<dim3(128, 8), 256, 0, stream>>>(h1b, wt1, ftb1, resf1);
    elr1_kernel<<<NN / 4, 256, 0, stream>>>(ftb1, al1, ar1, el1, er1);
    alpha_kernel<false><<<NN / 4, 256, 0, stream>>>(row, eid, src, srcs, el1, er1, alpha1, inv1);
    agg1_kernel<<<NN / 4, 256, 0, stream>>>(ftb1, resf1, row, srcs, alpha1, inv1, b1, h2);

    // readout + MLP
    readout1_kernel<<<GG * 16, 256, 0, stream>>>(h2, part);
    readout2_kernel<<<GG, 256, 0, stream>>>(part, mW0, mb0, mW1, mb1, mW2, mb2, out);
}

// Round 6
// 165.927 us; speedup vs baseline: 3.3273x; 1.1357x over previous
//
#include <hip/hip_runtime.h>
#include <hip/hip_bf16.h>

#define NN 16384
#define EE 262144
#define GG 32
#define NPGC 512
#define NEG_SLOPE 0.2f

typedef __attribute__((ext_vector_type(8))) short bf16x8;
typedef __attribute__((ext_vector_type(4))) float f32x4;

__device__ __forceinline__ float b2f(short s) {
    union { float f; unsigned u; } c;
    c.u = ((unsigned)(unsigned short)s) << 16;
    return c.f;
}

__device__ __forceinline__ short f2b(float f) {
    __hip_bfloat16 b = __float2bfloat16(f);
    short r;
    __builtin_memcpy(&r, &b, 2);
    return r;
}

// ---------------- build h = [aa_emb[ref]*aa_emb[alt[gid]] | feat] (bf16) ----------------
__global__ __launch_bounds__(320) void build_h_kernel(
    const float* __restrict__ feat, const float* __restrict__ aa_emb,
    const int* __restrict__ ref_aa, const int* __restrict__ alt_aa,
    const int* __restrict__ graph_id, __hip_bfloat16* __restrict__ h)
{
    int n = blockIdx.x, t = threadIdx.x;
    float v;
    if (t < 64) {
        int ra = ref_aa[n], ga = alt_aa[graph_id[n]];
        v = aa_emb[ra * 64 + t] * aa_emb[ga * 64 + t];
    } else {
        v = feat[(size_t)n * 256 + (t - 64)];
    }
    h[(size_t)n * 320 + t] = __float2bfloat16(v);
}

// ---------------- weight transpose+cast ----------------
__global__ __launch_bounds__(256) void wtrans_kernel(
    const float* __restrict__ W, const float* __restrict__ R,
    int K, int C1, __hip_bfloat16* __restrict__ out)
{
    int k = blockIdx.x * 256 + threadIdx.x;
    int c = blockIdx.y;
    if (k >= K) return;
    float v = (c < C1) ? W[(size_t)k * C1 + c] : R[(size_t)k * C1 + (c - C1)];
    out[(size_t)c * K + k] = __float2bfloat16(v);
}

// ---------------- CSR build ----------------
__global__ __launch_bounds__(256) void deg_kernel(const int* __restrict__ dst, int* __restrict__ deg)
{
    int i = blockIdx.x * 256 + threadIdx.x;
    if (i < EE) atomicAdd(&deg[dst[i]], 1);
}

__global__ __launch_bounds__(256) void scan_kernel(const int* __restrict__ deg,
                                                   int* __restrict__ row, int* __restrict__ cursor)
{
    __shared__ int part[256];
    __shared__ int pref[257];
    int t = threadIdx.x, base = t * 64;
    int s = 0;
    for (int i = 0; i < 64; i++) s += deg[base + i];
    part[t] = s;
    __syncthreads();
    if (t == 0) {
        int a = 0;
        for (int i = 0; i < 256; i++) { pref[i] = a; a += part[i]; }
        pref[256] = a;
    }
    __syncthreads();
    int a = pref[t];
    for (int i = 0; i < 64; i++) {
        row[base + i] = a; cursor[base + i] = a;
        a += deg[base + i];
    }
    if (t == 0) row[NN] = pref[256];
}

// scatter src node ids directly into dst-sorted order
__global__ __launch_bounds__(256) void scatter_kernel(
    const int* __restrict__ src, const int* __restrict__ dst,
    int* __restrict__ cursor, int* __restrict__ srcs)
{
    int i = blockIdx.x * 256 + threadIdx.x;
    if (i < EE) {
        int p = atomicAdd(&cursor[dst[i]], 1);
        srcs[p] = src[i];
    }
}

// ---------------- MFMA GEMM: split bf16 output [ftb | resb] ----------------
template<int FR, int C1, int KTOT>
__global__ __launch_bounds__(256) void mfma_gemm_kernel(
    const __hip_bfloat16* __restrict__ A, const __hip_bfloat16* __restrict__ Bt,
    __hip_bfloat16* __restrict__ ftb, __hip_bfloat16* __restrict__ resb)
{
    constexpr int BM = 32 * FR;
    __shared__ short As[BM * 64];
    __shared__ short Bs[BM * 64];
    int t = threadIdx.x;
    int wid = t >> 6, lane = t & 63;
    int wr = wid >> 1, wc = wid & 1;
    int row0 = blockIdx.x * BM, col0 = blockIdx.y * BM;

    f32x4 acc[FR][FR];
#pragma unroll
    for (int m = 0; m < FR; m++)
#pragma unroll
        for (int n = 0; n < FR; n++) acc[m][n] = (f32x4){0.f, 0.f, 0.f, 0.f};

    for (int kk = 0; kk < KTOT; kk += 64) {
        __syncthreads();
#pragma unroll
        for (int c = t; c < BM * 8; c += 256) {
            int row = c >> 3, slot = c & 7;
            int sw = (slot ^ (row & 7)) * 8;
            bf16x8 va = *(const bf16x8*)(A + (size_t)(row0 + row) * KTOT + kk + slot * 8);
            *(bf16x8*)(&As[row * 64 + sw]) = va;
            bf16x8 vb = *(const bf16x8*)(Bt + (size_t)(col0 + row) * KTOT + kk + slot * 8);
            *(bf16x8*)(&Bs[row * 64 + sw]) = vb;
        }
        __syncthreads();
#pragma unroll
        for (int ks = 0; ks < 2; ks++) {
            int kslot = ks * 4 + (lane >> 4);
            bf16x8 a[FR], b[FR];
#pragma unroll
            for (int m = 0; m < FR; m++) {
                int row = wr * FR * 16 + m * 16 + (lane & 15);
                a[m] = *(const bf16x8*)(&As[row * 64 + ((kslot ^ (row & 7)) * 8)]);
            }
#pragma unroll
            for (int n = 0; n < FR; n++) {
                int col = wc * FR * 16 + n * 16 + (lane & 15);
                b[n] = *(const bf16x8*)(&Bs[col * 64 + ((kslot ^ (col & 7)) * 8)]);
            }
#pragma unroll
            for (int m = 0; m < FR; m++)
#pragma unroll
                for (int n = 0; n < FR; n++)
                    acc[m][n] = __builtin_amdgcn_mfma_f32_16x16x32_bf16(a[m], b[n], acc[m][n], 0, 0, 0);
        }
    }

#pragma unroll
    for (int m = 0; m < FR; m++)
#pragma unroll
        for (int n = 0; n < FR; n++) {
            int colg = col0 + wc * FR * 16 + n * 16 + (lane & 15);
            int rbase = row0 + wr * FR * 16 + m * 16 + (lane >> 4) * 4;
#pragma unroll
            for (int r = 0; r < 4; r++) {
                float v = acc[m][n][r];
                int rg = rbase + r;
                if (colg < C1) ftb[(size_t)rg * C1 + colg] = __float2bfloat16(v);
                else           resb[(size_t)rg * C1 + (colg - C1)] = __float2bfloat16(v);
            }
        }
}

// ---------------- layer0 el/er (scalar, O=64) ----------------
__global__ __launch_bounds__(256) void elr0_kernel(
    const __hip_bfloat16* __restrict__ ftb,
    const float* __restrict__ al, const float* __restrict__ ar,
    float* __restrict__ el, float* __restrict__ er)
{
    int gid = blockIdx.x * 256 + threadIdx.x;
    int wv = gid >> 6, lane = gid & 63;
    int n = wv >> 1, hh = wv & 1;
    if (n >= NN) return;
    float f = b2f(((const short*)ftb)[(size_t)n * 128 + hh * 64 + lane]);
    float sl = f * al[hh * 64 + lane];
    float sr = f * ar[hh * 64 + lane];
#pragma unroll
    for (int d = 32; d; d >>= 1) { sl += __shfl_xor(sl, d); sr += __shfl_xor(sr, d); }
    if (lane == 0) { el[n * 2 + hh] = sl; er[n * 2 + hh] = sr; }
}

// ---------------- layer1 el/er: one wave per node, vectorized ----------------
__global__ __launch_bounds__(256) void elr1_kernel(
    const __hip_bfloat16* __restrict__ ftb,
    const float* __restrict__ al, const float* __restrict__ ar,
    float* __restrict__ el, float* __restrict__ er)
{
    int wv = (blockIdx.x * 256 + threadIdx.x) >> 6;
    int lane = threadIdx.x & 63;
    if (wv >= NN) return;
    int n = wv, hh = lane >> 5, dim = lane * 8;
    bf16x8 v = *(const bf16x8*)((const short*)ftb + (size_t)n * 512 + dim);
    float sl = 0.f, sr = 0.f;
#pragma unroll
    for (int j = 0; j < 8; j++) {
        float f = b2f(v[j]);
        sl += f * al[dim + j];
        sr += f * ar[dim + j];
    }
#pragma unroll
    for (int d = 16; d; d >>= 1) { sl += __shfl_xor(sl, d); sr += __shfl_xor(sr, d); }
    if ((lane & 31) == 0) { el[n * 2 + hh] = sl; er[n * 2 + hh] = sr; }
}

// ---------------- layer0 fused softmax+aggregation -> h1 (bf16) ----------------
// One wave per node. Phase A: lane=edge computes w=exp(leaky(el+er)) (no max shift:
// |e| <= ~10 so exp is safe; ratios identical to shifted form up to rounding).
// Phase B: 4 edge-groups x 16 dim-lanes; src/w broadcast via __shfl (readlane).
__global__ __launch_bounds__(256) void agg0_kernel(
    const __hip_bfloat16* __restrict__ ftb0, const __hip_bfloat16* __restrict__ resb0,
    const int* __restrict__ row, const int* __restrict__ srcs,
    const float* __restrict__ el, const float* __restrict__ er,
    const float* __restrict__ b0, __hip_bfloat16* __restrict__ h1)
{
    int wv = (blockIdx.x * 256 + threadIdx.x) >> 6;
    int lane = threadIdx.x & 63;
    if (wv >= NN) return;
    int n = wv;
    int eo = lane >> 4, vo = lane & 15;
    int hh = vo >> 3, dim = vo * 8;
    int e0 = row[n], e1 = row[n + 1];
    float er0v = er[n * 2 + 0], er1v = er[n * 2 + 1];

    float acc[8] = {0.f, 0.f, 0.f, 0.f, 0.f, 0.f, 0.f, 0.f};
    float ts0 = 0.f, ts1 = 0.f;
    for (int base = e0; base < e1; base += 64) {
        int c = min(64, e1 - base);
        float w0 = 0.f, w1 = 0.f;
        int sm = -1;
        if (lane < c) {
            sm = srcs[base + lane];
            float v0 = el[sm * 2 + 0] + er0v; v0 = v0 > 0.f ? v0 : NEG_SLOPE * v0;
            float v1 = el[sm * 2 + 1] + er1v; v1 = v1 > 0.f ? v1 : NEG_SLOPE * v1;
            w0 = __expf(v0); w1 = __expf(v1);
        }
        ts0 += w0; ts1 += w1;
        for (int i = eo; i < c; i += 4) {
            int s = __shfl(sm, i);
            float a0 = __shfl(w0, i), a1 = __shfl(w1, i);
            float a = hh ? a1 : a0;
            bf16x8 v = *(const bf16x8*)((const short*)ftb0 + (size_t)s * 128 + dim);
#pragma unroll
            for (int j = 0; j < 8; j++) acc[j] += a * b2f(v[j]);
        }
    }
#pragma unroll
    for (int d = 32; d; d >>= 1) { ts0 += __shfl_xor(ts0, d); ts1 += __shfl_xor(ts1, d); }
#pragma unroll
    for (int j = 0; j < 8; j++) acc[j] += __shfl_xor(acc[j], 16);
#pragma unroll
    for (int j = 0; j < 8; j++) acc[j] += __shfl_xor(acc[j], 32);
    if (eo == 0) {
        float s = hh ? ts1 : ts0;
        float invv = s > 0.f ? 1.f / s : 0.f;
        bf16x8 res = *(const bf16x8*)((const short*)resb0 + (size_t)n * 128 + dim);
        bf16x8 o;
#pragma unroll
        for (int j = 0; j < 8; j++) {
            float r = acc[j] * invv + b2f(res[j]) + b0[dim + j];
            r = r > 0.f ? r : (__expf(r) - 1.f);
            o[j] = f2b(r);
        }
        *(bf16x8*)((short*)h1 + (size_t)n * 128 + dim) = o;
    }
}

// ---------------- layer1 fused softmax+aggregation + head-mean + ELU -> h2 ----------------
__global__ __launch_bounds__(256) void agg1_kernel(
    const __hip_bfloat16* __restrict__ ftb1, const __hip_bfloat16* __restrict__ resb1,
    const int* __restrict__ row, const int* __restrict__ srcs,
    const float* __restrict__ el, const float* __restrict__ er,
    const float* __restrict__ b1, float* __restrict__ h2)
{
    int wv = (blockIdx.x * 256 + threadIdx.x) >> 6;
    int lane = threadIdx.x & 63;
    if (wv >= NN) return;
    int n = wv;
    int hh = lane >> 5, dim = lane * 8;
    int e0 = row[n], e1 = row[n + 1];
    float er0v = er[n * 2 + 0], er1v = er[n * 2 + 1];

    float acc[8] = {0.f, 0.f, 0.f, 0.f, 0.f, 0.f, 0.f, 0.f};
    float ts0 = 0.f, ts1 = 0.f;
    for (int base = e0; base < e1; base += 64) {
        int c = min(64, e1 - base);
        float w0 = 0.f, w1 = 0.f;
        int sm = -1;
        if (lane < c) {
            sm = srcs[base + lane];
            float v0 = el[sm * 2 + 0] + er0v; v0 = v0 > 0.f ? v0 : NEG_SLOPE * v0;
            float v1 = el[sm * 2 + 1] + er1v; v1 = v1 > 0.f ? v1 : NEG_SLOPE * v1;
            w0 = __expf(v0); w1 = __expf(v1);
        }
        ts0 += w0; ts1 += w1;
        int i = 0;
        for (; i + 4 <= c; i += 4) {
            int sA = __shfl(sm, i),     sB = __shfl(sm, i + 1);
            int sC = __shfl(sm, i + 2), sD = __shfl(sm, i + 3);
            float a0A = __shfl(w0, i),     a1A = __shfl(w1, i);
            float a0B = __shfl(w0, i + 1), a1B = __shfl(w1, i + 1);
            float a0C = __shfl(w0, i + 2), a1C = __shfl(w1, i + 2);
            float a0D = __shfl(w0, i + 3), a1D = __shfl(w1, i + 3);
            float aA = hh ? a1A : a0A, aB = hh ? a1B : a0B;
            float aC = hh ? a1C : a0C, aD = hh ? a1D : a0D;
            bf16x8 vA = *(const bf16x8*)((const short*)ftb1 + (size_t)sA * 512 + dim);
            bf16x8 vB = *(const bf16x8*)((const short*)ftb1 + (size_t)sB * 512 + dim);
            bf16x8 vC = *(const bf16x8*)((const short*)ftb1 + (size_t)sC * 512 + dim);
            bf16x8 vD = *(const bf16x8*)((const short*)ftb1 + (size_t)sD * 512 + dim);
#pragma unroll
            for (int j = 0; j < 8; j++) {
                acc[j] += aA * b2f(vA[j]) + aB * b2f(vB[j]) + aC * b2f(vC[j]) + aD * b2f(vD[j]);
            }
        }
        for (; i < c; i++) {
            int s = __shfl(sm, i);
            float a0 = __shfl(w0, i), a1 = __shfl(w1, i);
            float a = hh ? a1 : a0;
            bf16x8 v = *(const bf16x8*)((const short*)ftb1 + (size_t)s * 512 + dim);
#pragma unroll
            for (int j = 0; j < 8; j++) acc[j] += a * b2f(v[j]);
        }
    }
#pragma unroll
    for (int d = 32; d; d >>= 1) { ts0 += __shfl_xor(ts0, d); ts1 += __shfl_xor(ts1, d); }
    float s = hh ? ts1 : ts0;
    float invv = s > 0.f ? 1.f / s : 0.f;

    bf16x8 res = *(const bf16x8*)((const short*)resb1 + (size_t)n * 512 + dim);
    float r[8];
#pragma unroll
    for (int j = 0; j < 8; j++)
        r[j] = acc[j] * invv + b2f(res[j]) + b1[dim + j];
    float v[8];
#pragma unroll
    for (int j = 0; j < 8; j++) {
        float o = __shfl_xor(r[j], 32);
        v[j] = 0.5f * (r[j] + o);
    }
    if (lane < 32) {
#pragma unroll
        for (int j = 0; j < 8; j++) {
            float x = v[j];
            v[j] = x > 0.f ? x : (__expf(x) - 1.f);
        }
        float* outp = h2 + (size_t)n * 256 + lane * 8;
        *(f32x4*)outp = (f32x4){v[0], v[1], v[2], v[3]};
        *(f32x4*)(outp + 4) = (f32x4){v[4], v[5], v[6], v[7]};
    }
}

// ---------------- readout stage 1: partial sums over 32-node chunks ----------------
__global__ __launch_bounds__(256) void readout1_kernel(
    const float* __restrict__ h2, float* __restrict__ part)
{
    int blk = blockIdx.x;           // g*16 + c
    int g = blk >> 4, c = blk & 15;
    int t = threadIdx.x;
    float s = 0.f;
    int base = g * NPGC + c * 32;
    for (int i = 0; i < 32; i++) s += h2[(size_t)(base + i) * 256 + t];
    part[(size_t)blk * 256 + t] = s;
}

// ---------------- readout stage 2: combine + MLP ----------------
__global__ __launch_bounds__(256) void readout2_kernel(
    const float* __restrict__ part,
    const float* __restrict__ mW0, const float* __restrict__ mb0,
    const float* __restrict__ mW1, const float* __restrict__ mb1,
    const float* __restrict__ mW2, const float* __restrict__ mb2,
    float* __restrict__ out)
{
    __shared__ float hg[256];
    __shared__ float x1[128];
    __shared__ float x2[64];
    int g = blockIdx.x, t = threadIdx.x;
    float s = 0.f;
    for (int c = 0; c < 16; c++) s += part[(size_t)(g * 16 + c) * 256 + t];
    hg[t] = s * (1.f / (float)NPGC);
    __syncthreads();
    if (t < 128) {
        float a = mb0[t];
        for (int k = 0; k < 256; k++) a += hg[k] * mW0[k * 128 + t];
        x1[t] = fmaxf(a, 0.f);
    }
    __syncthreads();
    if (t < 64) {
        float a = mb1[t];
        for (int k = 0; k < 128; k++) a += x1[k] * mW1[k * 64 + t];
        x2[t] = fmaxf(a, 0.f);
    }
    __syncthreads();
    if (t < 2) {
        float a = mb2[t];
        for (int k = 0; k < 64; k++) a += x2[k] * mW2[k * 2 + t];
        out[g * 2 + t] = a;
    }
}

extern "C" void kernel_launch(void* const* d_in, const int* in_sizes, int n_in,
                              void* d_out, int out_size, void* d_ws, size_t ws_size,
                              hipStream_t stream)
{
    const float* feat   = (const float*)d_in[0];
    const float* aa_emb = (const float*)d_in[1];
    const float* W0     = (const float*)d_in[2];
    const float* al0    = (const float*)d_in[3];
    const float* ar0    = (const float*)d_in[4];
    const float* res0   = (const float*)d_in[5];
    const float* b0     = (const float*)d_in[6];
    const float* W1     = (const float*)d_in[7];
    const float* al1    = (const float*)d_in[8];
    const float* ar1    = (const float*)d_in[9];
    const float* res1   = (const float*)d_in[10];
    const float* b1     = (const float*)d_in[11];
    const float* mW0    = (const float*)d_in[12];
    const float* mb0    = (const float*)d_in[13];
    const float* mW1    = (const float*)d_in[14];
    const float* mb1    = (const float*)d_in[15];
    const float* mW2    = (const float*)d_in[16];
    const float* mb2    = (const float*)d_in[17];
    const int* ref_aa   = (const int*)d_in[18];
    const int* alt_aa   = (const int*)d_in[19];
    const int* src      = (const int*)d_in[20];
    const int* dst      = (const int*)d_in[21];
    const int* graph_id = (const int*)d_in[22];
    float* out = (float*)d_out;

    size_t off = 0;
    auto alloc = [&](size_t bytes) -> void* {
        void* p = (char*)d_ws + off;
        off += (bytes + 255) & ~(size_t)255;
        return p;
    };
    __hip_bfloat16* h    = (__hip_bfloat16*)alloc((size_t)NN * 320 * 2);
    __hip_bfloat16* wt0  = (__hip_bfloat16*)alloc((size_t)256 * 320 * 2);
    __hip_bfloat16* wt1  = (__hip_bfloat16*)alloc((size_t)1024 * 128 * 2);
    __hip_bfloat16* ftb0 = (__hip_bfloat16*)alloc((size_t)NN * 128 * 2);
    __hip_bfloat16* resb0 = (__hip_bfloat16*)alloc((size_t)NN * 128 * 2);
    __hip_bfloat16* h1b  = (__hip_bfloat16*)alloc((size_t)NN * 128 * 2);
    __hip_bfloat16* ftb1 = (__hip_bfloat16*)alloc((size_t)NN * 512 * 2);
    __hip_bfloat16* resb1 = (__hip_bfloat16*)alloc((size_t)NN * 512 * 2);
    float* h2     = (float*)alloc((size_t)NN * 256 * 4);
    float* el0    = (float*)alloc((size_t)NN * 2 * 4);
    float* er0    = (float*)alloc((size_t)NN * 2 * 4);
    float* el1    = (float*)alloc((size_t)NN * 2 * 4);
    float* er1    = (float*)alloc((size_t)NN * 2 * 4);
    int* deg      = (int*)alloc((size_t)NN * 4);
    int* row      = (int*)alloc((size_t)(NN + 1) * 4);
    int* cursor   = (int*)alloc((size_t)NN * 4);
    int* srcs     = (int*)alloc((size_t)EE * 4);
    float* part   = (float*)alloc((size_t)GG * 16 * 256 * 4);

    (void)in_sizes; (void)n_in; (void)out_size; (void)ws_size;

    (void)hipMemsetAsync(deg, 0, (size_t)NN * 4, stream);
    build_h_kernel<<<NN, 320, 0, stream>>>(feat, aa_emb, ref_aa, alt_aa, graph_id, h);
    wtrans_kernel<<<dim3(2, 256), 256, 0, stream>>>(W0, res0, 320, 128, wt0);
    wtrans_kernel<<<dim3(1, 1024), 256, 0, stream>>>(W1, res1, 128, 512, wt1);
    deg_kernel<<<EE / 256, 256, 0, stream>>>(dst, deg);
    scan_kernel<<<1, 256, 0, stream>>>(deg, row, cursor);
    scatter_kernel<<<EE / 256, 256, 0, stream>>>(src, dst, cursor, srcs);

    // layer 0
    mfma_gemm_kernel<2, 128, 320><<<dim3(256, 4), 256, 0, stream>>>(h, wt0, ftb0, resb0);
    elr0_kernel<<<(NN * 2 * 64) / 256, 256, 0, stream>>>(ftb0, al0, ar0, el0, er0);
    agg0_kernel<<<NN / 4, 256, 0, stream>>>(ftb0, resb0, row, srcs, el0, er0, b0, h1b);

    // layer 1
    mfma_gemm_kernel<4, 512, 128><<<dim3(128, 8), 256, 0, stream>>>(h1b, wt1, ftb1, resb1);
    elr1_kernel<<<NN / 4, 256, 0, stream>>>(ftb1, al1, ar1, el1, er1);
    agg1_kernel<<<NN / 4, 256, 0, stream>>>(ftb1, resb1, row, srcs, el1, er1, b1, h2);

    // readout + MLP
    readout1_kernel<<<GG * 16, 256, 0, stream>>>(h2, part);
    readout2_kernel<<<GG, 256, 0, stream>>>(part, mW0, mb0, mW1, mb1, mW2, mb2, out);
}

// Round 9
// 165.542 us; speedup vs baseline: 3.3351x; 1.0023x over previous
//
#include <hip/hip_runtime.h>
#include <hip/hip_bf16.h>

#define NN 16384
#define EE 262144
#define GG 32
#define NPGC 512
#define NEG_SLOPE 0.2f

typedef __attribute__((ext_vector_type(8))) short bf16x8;
typedef __attribute__((ext_vector_type(4))) float f32x4;

__device__ __forceinline__ float b2f(short s) {
    union { float f; unsigned u; } c;
    c.u = ((unsigned)(unsigned short)s) << 16;
    return c.f;
}

__device__ __forceinline__ short f2b(float f) {
    __hip_bfloat16 b = __float2bfloat16(f);
    short r;
    __builtin_memcpy(&r, &b, 2);
    return r;
}

// ---------------- build h = [aa_emb[ref]*aa_emb[alt[gid]] | feat] (bf16); also zero deg ----------------
__global__ __launch_bounds__(320) void build_h_kernel(
    const float* __restrict__ feat, const float* __restrict__ aa_emb,
    const int* __restrict__ ref_aa, const int* __restrict__ alt_aa,
    const int* __restrict__ graph_id, __hip_bfloat16* __restrict__ h,
    int* __restrict__ deg)
{
    int n = blockIdx.x, t = threadIdx.x;
    if (t == 0) deg[n] = 0;
    float v;
    if (t < 64) {
        int ra = ref_aa[n], ga = alt_aa[graph_id[n]];
        v = aa_emb[ra * 64 + t] * aa_emb[ga * 64 + t];
    } else {
        v = feat[(size_t)n * 256 + (t - 64)];
    }
    h[(size_t)n * 320 + t] = __float2bfloat16(v);
}

// ---------------- merged weight transpose+cast for both layers ----------------
__global__ __launch_bounds__(256) void wtrans_kernel(
    const float* __restrict__ W0, const float* __restrict__ R0,
    const float* __restrict__ W1, const float* __restrict__ R1,
    __hip_bfloat16* __restrict__ wt0, __hip_bfloat16* __restrict__ wt1)
{
    int k = blockIdx.x * 256 + threadIdx.x;
    int c = blockIdx.y;
    if (c < 256) {                       // layer0: K=320, C=256
        if (k >= 320) return;
        float v = (c < 128) ? W0[(size_t)k * 128 + c] : R0[(size_t)k * 128 + (c - 128)];
        wt0[(size_t)c * 320 + k] = __float2bfloat16(v);
    } else {                             // layer1: K=128, C=1024
        int cc = c - 256;
        if (k >= 128) return;
        float v = (cc < 512) ? W1[(size_t)k * 512 + cc] : R1[(size_t)k * 512 + (cc - 512)];
        wt1[(size_t)cc * 128 + k] = __float2bfloat16(v);
    }
}

// ---------------- CSR build ----------------
__global__ __launch_bounds__(256) void deg_kernel(const int* __restrict__ dst, int* __restrict__ deg)
{
    int i = blockIdx.x * 256 + threadIdx.x;
    if (i < EE) atomicAdd(&deg[dst[i]], 1);
}

__global__ __launch_bounds__(256) void scan_kernel(const int* __restrict__ deg,
                                                   int* __restrict__ row, int* __restrict__ cursor)
{
    __shared__ int part[256];
    __shared__ int pref[257];
    int t = threadIdx.x, base = t * 64;
    int s = 0;
    for (int i = 0; i < 64; i++) s += deg[base + i];
    part[t] = s;
    __syncthreads();
    if (t == 0) {
        int a = 0;
        for (int i = 0; i < 256; i++) { pref[i] = a; a += part[i]; }
        pref[256] = a;
    }
    __syncthreads();
    int a = pref[t];
    for (int i = 0; i < 64; i++) {
        row[base + i] = a; cursor[base + i] = a;
        a += deg[base + i];
    }
    if (t == 0) row[NN] = pref[256];
}

// scatter src node ids directly into dst-sorted order
__global__ __launch_bounds__(256) void scatter_kernel(
    const int* __restrict__ src, const int* __restrict__ dst,
    int* __restrict__ cursor, int* __restrict__ srcs)
{
    int i = blockIdx.x * 256 + threadIdx.x;
    if (i < EE) {
        int p = atomicAdd(&cursor[dst[i]], 1);
        srcs[p] = src[i];
    }
}

// ---------------- MFMA GEMM: split output [ftb(bf16) | resf(f32)] ----------------
template<int FR, int C1, int KTOT>
__global__ __launch_bounds__(256) void mfma_gemm_kernel(
    const __hip_bfloat16* __restrict__ A, const __hip_bfloat16* __restrict__ Bt,
    __hip_bfloat16* __restrict__ ftb, float* __restrict__ resf)
{
    constexpr int BM = 32 * FR;
    __shared__ short As[BM * 64];
    __shared__ short Bs[BM * 64];
    int t = threadIdx.x;
    int wid = t >> 6, lane = t & 63;
    int wr = wid >> 1, wc = wid & 1;
    int row0 = blockIdx.x * BM, col0 = blockIdx.y * BM;

    f32x4 acc[FR][FR];
#pragma unroll
    for (int m = 0; m < FR; m++)
#pragma unroll
        for (int n = 0; n < FR; n++) acc[m][n] = (f32x4){0.f, 0.f, 0.f, 0.f};

    for (int kk = 0; kk < KTOT; kk += 64) {
        __syncthreads();
#pragma unroll
        for (int c = t; c < BM * 8; c += 256) {
            int row = c >> 3, slot = c & 7;
            int sw = (slot ^ (row & 7)) * 8;
            bf16x8 va = *(const bf16x8*)(A + (size_t)(row0 + row) * KTOT + kk + slot * 8);
            *(bf16x8*)(&As[row * 64 + sw]) = va;
            bf16x8 vb = *(const bf16x8*)(Bt + (size_t)(col0 + row) * KTOT + kk + slot * 8);
            *(bf16x8*)(&Bs[row * 64 + sw]) = vb;
        }
        __syncthreads();
#pragma unroll
        for (int ks = 0; ks < 2; ks++) {
            int kslot = ks * 4 + (lane >> 4);
            bf16x8 a[FR], b[FR];
#pragma unroll
            for (int m = 0; m < FR; m++) {
                int row = wr * FR * 16 + m * 16 + (lane & 15);
                a[m] = *(const bf16x8*)(&As[row * 64 + ((kslot ^ (row & 7)) * 8)]);
            }
#pragma unroll
            for (int n = 0; n < FR; n++) {
                int col = wc * FR * 16 + n * 16 + (lane & 15);
                b[n] = *(const bf16x8*)(&Bs[col * 64 + ((kslot ^ (col & 7)) * 8)]);
            }
#pragma unroll
            for (int m = 0; m < FR; m++)
#pragma unroll
                for (int n = 0; n < FR; n++)
                    acc[m][n] = __builtin_amdgcn_mfma_f32_16x16x32_bf16(a[m], b[n], acc[m][n], 0, 0, 0);
        }
    }

#pragma unroll
    for (int m = 0; m < FR; m++)
#pragma unroll
        for (int n = 0; n < FR; n++) {
            int colg = col0 + wc * FR * 16 + n * 16 + (lane & 15);
            int rbase = row0 + wr * FR * 16 + m * 16 + (lane >> 4) * 4;
#pragma unroll
            for (int r = 0; r < 4; r++) {
                float v = acc[m][n][r];
                int rg = rbase + r;
                if (colg < C1) ftb[(size_t)rg * C1 + colg] = __float2bfloat16(v);
                else           resf[(size_t)rg * C1 + (colg - C1)] = v;
            }
        }
}

// ---------------- layer0 el/er (scalar, O=64) ----------------
__global__ __launch_bounds__(256) void elr0_kernel(
    const __hip_bfloat16* __restrict__ ftb,
    const float* __restrict__ al, const float* __restrict__ ar,
    float* __restrict__ el, float* __restrict__ er)
{
    int gid = blockIdx.x * 256 + threadIdx.x;
    int wv = gid >> 6, lane = gid & 63;
    int n = wv >> 1, hh = wv & 1;
    if (n >= NN) return;
    float f = b2f(((const short*)ftb)[(size_t)n * 128 + hh * 64 + lane]);
    float sl = f * al[hh * 64 + lane];
    float sr = f * ar[hh * 64 + lane];
#pragma unroll
    for (int d = 32; d; d >>= 1) { sl += __shfl_xor(sl, d); sr += __shfl_xor(sr, d); }
    if (lane == 0) { el[n * 2 + hh] = sl; er[n * 2 + hh] = sr; }
}

// ---------------- layer1 el/er: one wave per node, vectorized ----------------
__global__ __launch_bounds__(256) void elr1_kernel(
    const __hip_bfloat16* __restrict__ ftb,
    const float* __restrict__ al, const float* __restrict__ ar,
    float* __restrict__ el, float* __restrict__ er)
{
    int wv = (blockIdx.x * 256 + threadIdx.x) >> 6;
    int lane = threadIdx.x & 63;
    if (wv >= NN) return;
    int n = wv, hh = lane >> 5, dim = lane * 8;
    bf16x8 v = *(const bf16x8*)((const short*)ftb + (size_t)n * 512 + dim);
    float sl = 0.f, sr = 0.f;
#pragma unroll
    for (int j = 0; j < 8; j++) {
        float f = b2f(v[j]);
        sl += f * al[dim + j];
        sr += f * ar[dim + j];
    }
#pragma unroll
    for (int d = 16; d; d >>= 1) { sl += __shfl_xor(sl, d); sr += __shfl_xor(sr, d); }
    if ((lane & 31) == 0) { el[n * 2 + hh] = sl; er[n * 2 + hh] = sr; }
}

// ---------------- layer0 fused softmax+aggregation -> h1 (bf16) [R5 structure] ----------------
__global__ __launch_bounds__(256) void agg0_kernel(
    const __hip_bfloat16* __restrict__ ftb0, const float* __restrict__ resf0,
    const int* __restrict__ row, const int* __restrict__ srcs,
    const float* __restrict__ el, const float* __restrict__ er,
    const float* __restrict__ b0, __hip_bfloat16* __restrict__ h1)
{
    int wv = (blockIdx.x * 256 + threadIdx.x) >> 6;
    int lane = threadIdx.x & 63;
    if (wv >= NN) return;
    int n = wv;
    int eo = lane >> 4, vo = lane & 15;
    int hh = vo >> 3, dim = vo * 8;
    int e0 = row[n], e1 = row[n + 1];
    float er0v = er[n * 2 + 0], er1v = er[n * 2 + 1];

    float acc[8] = {0.f, 0.f, 0.f, 0.f, 0.f, 0.f, 0.f, 0.f};
    float ts0 = 0.f, ts1 = 0.f;
    for (int base = e0; base < e1; base += 64) {
        int c = min(64, e1 - base);
        float w0 = 0.f, w1 = 0.f;
        int sm = -1;
        if (lane < c) {
            sm = srcs[base + lane];
            float v0 = el[sm * 2 + 0] + er0v; v0 = v0 > 0.f ? v0 : NEG_SLOPE * v0;
            float v1 = el[sm * 2 + 1] + er1v; v1 = v1 > 0.f ? v1 : NEG_SLOPE * v1;
            w0 = __expf(v0); w1 = __expf(v1);
        }
        ts0 += w0; ts1 += w1;
        for (int i = eo; i < c; i += 4) {
            int s = __shfl(sm, i);
            float a0 = __shfl(w0, i), a1 = __shfl(w1, i);
            float a = hh ? a1 : a0;
            bf16x8 v = *(const bf16x8*)((const short*)ftb0 + (size_t)s * 128 + dim);
#pragma unroll
            for (int j = 0; j < 8; j++) acc[j] += a * b2f(v[j]);
        }
    }
#pragma unroll
    for (int d = 32; d; d >>= 1) { ts0 += __shfl_xor(ts0, d); ts1 += __shfl_xor(ts1, d); }
#pragma unroll
    for (int j = 0; j < 8; j++) acc[j] += __shfl_xor(acc[j], 16);
#pragma unroll
    for (int j = 0; j < 8; j++) acc[j] += __shfl_xor(acc[j], 32);
    if (eo == 0) {
        float s = hh ? ts1 : ts0;
        float invv = s > 0.f ? 1.f / s : 0.f;
        const float* resp = resf0 + (size_t)n * 128 + dim;
        bf16x8 o;
#pragma unroll
        for (int j = 0; j < 8; j++) {
            float r = acc[j] * invv + resp[j] + b0[dim + j];
            r = r > 0.f ? r : (__expf(r) - 1.f);
            o[j] = f2b(r);
        }
        *(bf16x8*)((short*)h1 + (size_t)n * 128 + dim) = o;
    }
}

// ---------------- layer1 fused softmax+agg + head-mean + ELU -> h2 [R5 structure] ----------------
__global__ __launch_bounds__(256) void agg1_kernel(
    const __hip_bfloat16* __restrict__ ftb1, const float* __restrict__ resf1,
    const int* __restrict__ row, const int* __restrict__ srcs,
    const float* __restrict__ el, const float* __restrict__ er,
    const float* __restrict__ b1, float* __restrict__ h2)
{
    int wv = (blockIdx.x * 256 + threadIdx.x) >> 6;
    int lane = threadIdx.x & 63;
    if (wv >= NN) return;
    int n = wv;
    int hh = lane >> 5, dim = lane * 8;
    int e0 = row[n], e1 = row[n + 1];
    float er0v = er[n * 2 + 0], er1v = er[n * 2 + 1];

    float acc[8] = {0.f, 0.f, 0.f, 0.f, 0.f, 0.f, 0.f, 0.f};
    float ts0 = 0.f, ts1 = 0.f;
    for (int base = e0; base < e1; base += 64) {
        int c = min(64, e1 - base);
        float w0 = 0.f, w1 = 0.f;
        int sm = -1;
        if (lane < c) {
            sm = srcs[base + lane];
            float v0 = el[sm * 2 + 0] + er0v; v0 = v0 > 0.f ? v0 : NEG_SLOPE * v0;
            float v1 = el[sm * 2 + 1] + er1v; v1 = v1 > 0.f ? v1 : NEG_SLOPE * v1;
            w0 = __expf(v0); w1 = __expf(v1);
        }
        ts0 += w0; ts1 += w1;
        int i = 0;
        for (; i + 4 <= c; i += 4) {
            int sA = __shfl(sm, i),     sB = __shfl(sm, i + 1);
            int sC = __shfl(sm, i + 2), sD = __shfl(sm, i + 3);
            float a0A = __shfl(w0, i),     a1A = __shfl(w1, i);
            float a0B = __shfl(w0, i + 1), a1B = __shfl(w1, i + 1);
            float a0C = __shfl(w0, i + 2), a1C = __shfl(w1, i + 2);
            float a0D = __shfl(w0, i + 3), a1D = __shfl(w1, i + 3);
            float aA = hh ? a1A : a0A, aB = hh ? a1B : a0B;
            float aC = hh ? a1C : a0C, aD = hh ? a1D : a0D;
            bf16x8 vA = *(const bf16x8*)((const short*)ftb1 + (size_t)sA * 512 + dim);
            bf16x8 vB = *(const bf16x8*)((const short*)ftb1 + (size_t)sB * 512 + dim);
            bf16x8 vC = *(const bf16x8*)((const short*)ftb1 + (size_t)sC * 512 + dim);
            bf16x8 vD = *(const bf16x8*)((const short*)ftb1 + (size_t)sD * 512 + dim);
#pragma unroll
            for (int j = 0; j < 8; j++) {
                acc[j] += aA * b2f(vA[j]) + aB * b2f(vB[j]) + aC * b2f(vC[j]) + aD * b2f(vD[j]);
            }
        }
        for (; i < c; i++) {
            int s = __shfl(sm, i);
            float a0 = __shfl(w0, i), a1 = __shfl(w1, i);
            float a = hh ? a1 : a0;
            bf16x8 v = *(const bf16x8*)((const short*)ftb1 + (size_t)s * 512 + dim);
#pragma unroll
            for (int j = 0; j < 8; j++) acc[j] += a * b2f(v[j]);
        }
    }
#pragma unroll
    for (int d = 32; d; d >>= 1) { ts0 += __shfl_xor(ts0, d); ts1 += __shfl_xor(ts1, d); }
    float s = hh ? ts1 : ts0;
    float invv = s > 0.f ? 1.f / s : 0.f;

    const float* resp = resf1 + (size_t)n * 512 + dim;
    float r[8];
#pragma unroll
    for (int j = 0; j < 8; j++)
        r[j] = acc[j] * invv + resp[j] + b1[dim + j];
    float v[8];
#pragma unroll
    for (int j = 0; j < 8; j++) {
        float o = __shfl_xor(r[j], 32);
        v[j] = 0.5f * (r[j] + o);
    }
    if (lane < 32) {
#pragma unroll
        for (int j = 0; j < 8; j++) {
            float x = v[j];
            v[j] = x > 0.f ? x : (__expf(x) - 1.f);
        }
        float* outp = h2 + (size_t)n * 256 + lane * 8;
        *(f32x4*)outp = (f32x4){v[0], v[1], v[2], v[3]};
        *(f32x4*)(outp + 4) = (f32x4){v[4], v[5], v[6], v[7]};
    }
}

// ---------------- readout stage 1: partial sums over 32-node chunks ----------------
__global__ __launch_bounds__(256) void readout1_kernel(
    const float* __restrict__ h2, float* __restrict__ part)
{
    int blk = blockIdx.x;           // g*16 + c
    int g = blk >> 4, c = blk & 15;
    int t = threadIdx.x;
    float s = 0.f;
    int base = g * NPGC + c * 32;
    for (int i = 0; i < 32; i++) s += h2[(size_t)(base + i) * 256 + t];
    part[(size_t)blk * 256 + t] = s;
}

// ---------------- readout stage 2: combine + MLP ----------------
__global__ __launch_bounds__(256) void readout2_kernel(
    const float* __restrict__ part,
    const float* __restrict__ mW0, const float* __restrict__ mb0,
    const float* __restrict__ mW1, const float* __restrict__ mb1,
    const float* __restrict__ mW2, const float* __restrict__ mb2,
    float* __restrict__ out)
{
    __shared__ float hg[256];
    __shared__ float x1[128];
    __shared__ float x2[64];
    int g = blockIdx.x, t = threadIdx.x;
    float s = 0.f;
    for (int c = 0; c < 16; c++) s += part[(size_t)(g * 16 + c) * 256 + t];
    hg[t] = s * (1.f / (float)NPGC);
    __syncthreads();
    if (t < 128) {
        float a = mb0[t];
        for (int k = 0; k < 256; k++) a += hg[k] * mW0[k * 128 + t];
        x1[t] = fmaxf(a, 0.f);
    }
    __syncthreads();
    if (t < 64) {
        float a = mb1[t];
        for (int k = 0; k < 128; k++) a += x1[k] * mW1[k * 64 + t];
        x2[t] = fmaxf(a, 0.f);
    }
    __syncthreads();
    if (t < 2) {
        float a = mb2[t];
        for (int k = 0; k < 64; k++) a += x2[k] * mW2[k * 2 + t];
        out[g * 2 + t] = a;
    }
}

extern "C" void kernel_launch(void* const* d_in, const int* in_sizes, int n_in,
                              void* d_out, int out_size, void* d_ws, size_t ws_size,
                              hipStream_t stream)
{
    const float* feat   = (const float*)d_in[0];
    const float* aa_emb = (const float*)d_in[1];
    const float* W0     = (const float*)d_in[2];
    const float* al0    = (const float*)d_in[3];
    const float* ar0    = (const float*)d_in[4];
    const float* res0   = (const float*)d_in[5];
    const float* b0     = (const float*)d_in[6];
    const float* W1     = (const float*)d_in[7];
    const float* al1    = (const float*)d_in[8];
    const float* ar1    = (const float*)d_in[9];
    const float* res1   = (const float*)d_in[10];
    const float* b1     = (const float*)d_in[11];
    const float* mW0    = (const float*)d_in[12];
    const float* mb0    = (const float*)d_in[13];
    const float* mW1    = (const float*)d_in[14];
    const float* mb1    = (const float*)d_in[15];
    const float* mW2    = (const float*)d_in[16];
    const float* mb2    = (const float*)d_in[17];
    const int* ref_aa   = (const int*)d_in[18];
    const int* alt_aa   = (const int*)d_in[19];
    const int* src      = (const int*)d_in[20];
    const int* dst      = (const int*)d_in[21];
    const int* graph_id = (const int*)d_in[22];
    float* out = (float*)d_out;

    size_t off = 0;
    auto alloc = [&](size_t bytes) -> void* {
        void* p = (char*)d_ws + off;
        off += (bytes + 255) & ~(size_t)255;
        return p;
    };
    __hip_bfloat16* h    = (__hip_bfloat16*)alloc((size_t)NN * 320 * 2);
    __hip_bfloat16* wt0  = (__hip_bfloat16*)alloc((size_t)256 * 320 * 2);
    __hip_bfloat16* wt1  = (__hip_bfloat16*)alloc((size_t)1024 * 128 * 2);
    __hip_bfloat16* ftb0 = (__hip_bfloat16*)alloc((size_t)NN * 128 * 2);
    float* resf0  = (float*)alloc((size_t)NN * 128 * 4);
    __hip_bfloat16* h1b  = (__hip_bfloat16*)alloc((size_t)NN * 128 * 2);
    __hip_bfloat16* ftb1 = (__hip_bfloat16*)alloc((size_t)NN * 512 * 2);
    float* resf1  = (float*)alloc((size_t)NN * 512 * 4);
    float* h2     = (float*)alloc((size_t)NN * 256 * 4);
    float* el0    = (float*)alloc((size_t)NN * 2 * 4);
    float* er0    = (float*)alloc((size_t)NN * 2 * 4);
    float* el1    = (float*)alloc((size_t)NN * 2 * 4);
    float* er1    = (float*)alloc((size_t)NN * 2 * 4);
    int* deg      = (int*)alloc((size_t)NN * 4);
    int* row      = (int*)alloc((size_t)(NN + 1) * 4);
    int* cursor   = (int*)alloc((size_t)NN * 4);
    int* srcs     = (int*)alloc((size_t)EE * 4);
    float* part   = (float*)alloc((size_t)GG * 16 * 256 * 4);

    (void)in_sizes; (void)n_in; (void)out_size; (void)ws_size;

    build_h_kernel<<<NN, 320, 0, stream>>>(feat, aa_emb, ref_aa, alt_aa, graph_id, h, deg);
    wtrans_kernel<<<dim3(2, 1280), 256, 0, stream>>>(W0, res0, W1, res1, wt0, wt1);
    deg_kernel<<<EE / 256, 256, 0, stream>>>(dst, deg);
    scan_kernel<<<1, 256, 0, stream>>>(deg, row, cursor);
    scatter_kernel<<<EE / 256, 256, 0, stream>>>(src, dst, cursor, srcs);

    // layer 0
    mfma_gemm_kernel<2, 128, 320><<<dim3(256, 4), 256, 0, stream>>>(h, wt0, ftb0, resf0);
    elr0_kernel<<<(NN * 2 * 64) / 256, 256, 0, stream>>>(ftb0, al0, ar0, el0, er0);
    agg0_kernel<<<NN / 4, 256, 0, stream>>>(ftb0, resf0, row, srcs, el0, er0, b0, h1b);

    // layer 1
    mfma_gemm_kernel<4, 512, 128><<<dim3(128, 8), 256, 0, stream>>>(h1b, wt1, ftb1, resf1);
    elr1_kernel<<<NN / 4, 256, 0, stream>>>(ftb1, al1, ar1, el1, er1);
    agg1_kernel<<<NN / 4, 256, 0, stream>>>(ftb1, resf1, row, srcs, el1, er1, b1, h2);

    // readout + MLP
    readout1_kernel<<<GG * 16, 256, 0, stream>>>(h2, part);
    readout2_kernel<<<GG, 256, 0, stream>>>(part, mW0, mb0, mW1, mb1, mW2, mb2, out);
}

// Round 10
// 153.265 us; speedup vs baseline: 3.6022x; 1.0801x over previous
//
#include <hip/hip_runtime.h>
#include <hip/hip_bf16.h>

#define NN 16384
#define EE 262144
#define GG 32
#define NPGC 512
#define NEG_SLOPE 0.2f

typedef __attribute__((ext_vector_type(8))) short bf16x8;
typedef __attribute__((ext_vector_type(4))) float f32x4;

__device__ __forceinline__ float b2f(short s) {
    union { float f; unsigned u; } c;
    c.u = ((unsigned)(unsigned short)s) << 16;
    return c.f;
}

__device__ __forceinline__ short f2b(float f) {
    __hip_bfloat16 b = __float2bfloat16(f);
    short r;
    __builtin_memcpy(&r, &b, 2);
    return r;
}

// ---------------- k1 prep: build_h (+zero deg) U wtrans(layer0) U wtrans(layer1) ----------------
__global__ __launch_bounds__(320) void prep_kernel(
    const float* __restrict__ feat, const float* __restrict__ aa_emb,
    const int* __restrict__ ref_aa, const int* __restrict__ alt_aa,
    const int* __restrict__ graph_id, __hip_bfloat16* __restrict__ h,
    int* __restrict__ deg,
    const float* __restrict__ W0, const float* __restrict__ R0,
    const float* __restrict__ W1, const float* __restrict__ R1,
    __hip_bfloat16* __restrict__ wt0, __hip_bfloat16* __restrict__ wt1)
{
    int b = blockIdx.x, t = threadIdx.x;
    if (b < NN) {
        int n = b;
        if (t == 0) deg[n] = 0;
        float v;
        if (t < 64) {
            int ra = ref_aa[n], ga = alt_aa[graph_id[n]];
            v = aa_emb[ra * 64 + t] * aa_emb[ga * 64 + t];
        } else {
            v = feat[(size_t)n * 256 + (t - 64)];
        }
        h[(size_t)n * 320 + t] = __float2bfloat16(v);
    } else if (b < NN + 256) {
        int c = b - NN;   // layer0 col, K=320 == blockDim
        float v = (c < 128) ? W0[(size_t)t * 128 + c] : R0[(size_t)t * 128 + (c - 128)];
        wt0[(size_t)c * 320 + t] = __float2bfloat16(v);
    } else {
        int cc = b - NN - 256;  // layer1 col, K=128
        if (t < 128) {
            float v = (cc < 512) ? W1[(size_t)t * 512 + cc] : R1[(size_t)t * 512 + (cc - 512)];
            wt1[(size_t)cc * 128 + t] = __float2bfloat16(v);
        }
    }
}

// ---------------- MFMA GEMM body (LDS passed in; identical math to R8) ----------------
template<int FR, int C1, int KTOT>
__device__ __forceinline__ void gemm_body(
    const __hip_bfloat16* __restrict__ A, const __hip_bfloat16* __restrict__ Bt,
    __hip_bfloat16* __restrict__ ftb, float* __restrict__ resf,
    int bx, int by, short* lds)
{
    constexpr int BM = 32 * FR;
    short* As = lds;
    short* Bs = lds + BM * 64;
    int t = threadIdx.x;
    int wid = t >> 6, lane = t & 63;
    int wr = wid >> 1, wc = wid & 1;
    int row0 = bx * BM, col0 = by * BM;

    f32x4 acc[FR][FR];
#pragma unroll
    for (int m = 0; m < FR; m++)
#pragma unroll
        for (int n = 0; n < FR; n++) acc[m][n] = (f32x4){0.f, 0.f, 0.f, 0.f};

    for (int kk = 0; kk < KTOT; kk += 64) {
        __syncthreads();
#pragma unroll
        for (int c = t; c < BM * 8; c += 256) {
            int row = c >> 3, slot = c & 7;
            int sw = (slot ^ (row & 7)) * 8;
            bf16x8 va = *(const bf16x8*)(A + (size_t)(row0 + row) * KTOT + kk + slot * 8);
            *(bf16x8*)(&As[row * 64 + sw]) = va;
            bf16x8 vb = *(const bf16x8*)(Bt + (size_t)(col0 + row) * KTOT + kk + slot * 8);
            *(bf16x8*)(&Bs[row * 64 + sw]) = vb;
        }
        __syncthreads();
#pragma unroll
        for (int ks = 0; ks < 2; ks++) {
            int kslot = ks * 4 + (lane >> 4);
            bf16x8 a[FR], bfr[FR];
#pragma unroll
            for (int m = 0; m < FR; m++) {
                int row = wr * FR * 16 + m * 16 + (lane & 15);
                a[m] = *(const bf16x8*)(&As[row * 64 + ((kslot ^ (row & 7)) * 8)]);
            }
#pragma unroll
            for (int n = 0; n < FR; n++) {
                int col = wc * FR * 16 + n * 16 + (lane & 15);
                bfr[n] = *(const bf16x8*)(&Bs[col * 64 + ((kslot ^ (col & 7)) * 8)]);
            }
#pragma unroll
            for (int m = 0; m < FR; m++)
#pragma unroll
                for (int n = 0; n < FR; n++)
                    acc[m][n] = __builtin_amdgcn_mfma_f32_16x16x32_bf16(a[m], bfr[n], acc[m][n], 0, 0, 0);
        }
    }

#pragma unroll
    for (int m = 0; m < FR; m++)
#pragma unroll
        for (int n = 0; n < FR; n++) {
            int colg = col0 + wc * FR * 16 + n * 16 + (lane & 15);
            int rbase = row0 + wr * FR * 16 + m * 16 + (lane >> 4) * 4;
#pragma unroll
            for (int r = 0; r < 4; r++) {
                float v = acc[m][n][r];
                int rg = rbase + r;
                if (colg < C1) ftb[(size_t)rg * C1 + colg] = __float2bfloat16(v);
                else           resf[(size_t)rg * C1 + (colg - C1)] = v;
            }
        }
}

// ---------------- k2: gemm0 (blocks 0..1023) U deg count (blocks 1024..2047) ----------------
__global__ __launch_bounds__(256) void gemm0_deg_kernel(
    const __hip_bfloat16* __restrict__ A, const __hip_bfloat16* __restrict__ Bt,
    __hip_bfloat16* __restrict__ ftb, float* __restrict__ resf,
    const int* __restrict__ dst, int* __restrict__ deg)
{
    __shared__ short lds[2 * 64 * 64];
    int b = blockIdx.x;
    if (b < 1024) {
        gemm_body<2, 128, 320>(A, Bt, ftb, resf, b & 255, b >> 8, lds);
    } else {
        int i = (b - 1024) * 256 + threadIdx.x;
        if (i < EE) atomicAdd(&deg[dst[i]], 1);
    }
}

// ---------------- gemm1 standalone ----------------
__global__ __launch_bounds__(256) void gemm1_kernel(
    const __hip_bfloat16* __restrict__ A, const __hip_bfloat16* __restrict__ Bt,
    __hip_bfloat16* __restrict__ ftb, float* __restrict__ resf)
{
    __shared__ short lds[2 * 128 * 64];
    gemm_body<4, 512, 128>(A, Bt, ftb, resf, blockIdx.x, blockIdx.y, lds);
}

// ---------------- k3: scan (block 0) U elr0 (blocks 1..8192) ----------------
__global__ __launch_bounds__(256) void scan_elr0_kernel(
    const int* __restrict__ deg, int* __restrict__ row, int* __restrict__ cursor,
    const __hip_bfloat16* __restrict__ ftb,
    const float* __restrict__ al, const float* __restrict__ ar,
    float* __restrict__ el, float* __restrict__ er)
{
    int b = blockIdx.x, t = threadIdx.x;
    if (b == 0) {
        __shared__ int part[256];
        __shared__ int pref[257];
        int base = t * 64;
        int s = 0;
        for (int i = 0; i < 64; i++) s += deg[base + i];
        part[t] = s;
        __syncthreads();
        if (t == 0) {
            int a = 0;
            for (int i = 0; i < 256; i++) { pref[i] = a; a += part[i]; }
            pref[256] = a;
        }
        __syncthreads();
        int a = pref[t];
        for (int i = 0; i < 64; i++) {
            row[base + i] = a; cursor[base + i] = a;
            a += deg[base + i];
        }
        if (t == 0) row[NN] = pref[256];
    } else {
        int gid = (b - 1) * 256 + t;
        int wv = gid >> 6, lane = gid & 63;
        int n = wv >> 1, hh = wv & 1;
        if (n >= NN) return;
        float f = b2f(((const short*)ftb)[(size_t)n * 128 + hh * 64 + lane]);
        float sl = f * al[hh * 64 + lane];
        float sr = f * ar[hh * 64 + lane];
#pragma unroll
        for (int d = 32; d; d >>= 1) { sl += __shfl_xor(sl, d); sr += __shfl_xor(sr, d); }
        if (lane == 0) { el[n * 2 + hh] = sl; er[n * 2 + hh] = sr; }
    }
}

// scatter src node ids directly into dst-sorted order
__global__ __launch_bounds__(256) void scatter_kernel(
    const int* __restrict__ src, const int* __restrict__ dst,
    int* __restrict__ cursor, int* __restrict__ srcs)
{
    int i = blockIdx.x * 256 + threadIdx.x;
    if (i < EE) {
        int p = atomicAdd(&cursor[dst[i]], 1);
        srcs[p] = src[i];
    }
}

// ---------------- layer1 el/er: one wave per node, vectorized ----------------
__global__ __launch_bounds__(256) void elr1_kernel(
    const __hip_bfloat16* __restrict__ ftb,
    const float* __restrict__ al, const float* __restrict__ ar,
    float* __restrict__ el, float* __restrict__ er)
{
    int wv = (blockIdx.x * 256 + threadIdx.x) >> 6;
    int lane = threadIdx.x & 63;
    if (wv >= NN) return;
    int n = wv, hh = lane >> 5, dim = lane * 8;
    bf16x8 v = *(const bf16x8*)((const short*)ftb + (size_t)n * 512 + dim);
    float sl = 0.f, sr = 0.f;
#pragma unroll
    for (int j = 0; j < 8; j++) {
        float f = b2f(v[j]);
        sl += f * al[dim + j];
        sr += f * ar[dim + j];
    }
#pragma unroll
    for (int d = 16; d; d >>= 1) { sl += __shfl_xor(sl, d); sr += __shfl_xor(sr, d); }
    if ((lane & 31) == 0) { el[n * 2 + hh] = sl; er[n * 2 + hh] = sr; }
}

// ---------------- layer0 fused softmax+aggregation -> h1 (bf16) [R8 numerics] ----------------
__global__ __launch_bounds__(256) void agg0_kernel(
    const __hip_bfloat16* __restrict__ ftb0, const float* __restrict__ resf0,
    const int* __restrict__ row, const int* __restrict__ srcs,
    const float* __restrict__ el, const float* __restrict__ er,
    const float* __restrict__ b0, __hip_bfloat16* __restrict__ h1)
{
    int wv = (blockIdx.x * 256 + threadIdx.x) >> 6;
    int lane = threadIdx.x & 63;
    if (wv >= NN) return;
    int n = wv;
    int eo = lane >> 4, vo = lane & 15;
    int hh = vo >> 3, dim = vo * 8;
    int e0 = row[n], e1 = row[n + 1];
    float er0v = er[n * 2 + 0], er1v = er[n * 2 + 1];

    float acc[8] = {0.f, 0.f, 0.f, 0.f, 0.f, 0.f, 0.f, 0.f};
    float ts0 = 0.f, ts1 = 0.f;
    for (int base = e0; base < e1; base += 64) {
        int c = min(64, e1 - base);
        float w0 = 0.f, w1 = 0.f;
        int sm = -1;
        if (lane < c) {
            sm = srcs[base + lane];
            float v0 = el[sm * 2 + 0] + er0v; v0 = v0 > 0.f ? v0 : NEG_SLOPE * v0;
            float v1 = el[sm * 2 + 1] + er1v; v1 = v1 > 0.f ? v1 : NEG_SLOPE * v1;
            w0 = __expf(v0); w1 = __expf(v1);
        }
        ts0 += w0; ts1 += w1;
        for (int i = eo; i < c; i += 4) {
            int s = __shfl(sm, i);
            float a0 = __shfl(w0, i), a1 = __shfl(w1, i);
            float a = hh ? a1 : a0;
            bf16x8 v = *(const bf16x8*)((const short*)ftb0 + (size_t)s * 128 + dim);
#pragma unroll
            for (int j = 0; j < 8; j++) acc[j] += a * b2f(v[j]);
        }
    }
#pragma unroll
    for (int d = 32; d; d >>= 1) { ts0 += __shfl_xor(ts0, d); ts1 += __shfl_xor(ts1, d); }
#pragma unroll
    for (int j = 0; j < 8; j++) acc[j] += __shfl_xor(acc[j], 16);
#pragma unroll
    for (int j = 0; j < 8; j++) acc[j] += __shfl_xor(acc[j], 32);
    if (eo == 0) {
        float s = hh ? ts1 : ts0;
        float invv = s > 0.f ? 1.f / s : 0.f;
        const float* resp = resf0 + (size_t)n * 128 + dim;
        bf16x8 o;
#pragma unroll
        for (int j = 0; j < 8; j++) {
            float r = acc[j] * invv + resp[j] + b0[dim + j];
            r = r > 0.f ? r : (__expf(r) - 1.f);
            o[j] = f2b(r);
        }
        *(bf16x8*)((short*)h1 + (size_t)n * 128 + dim) = o;
    }
}

// ---------------- layer1 fused softmax+agg + head-mean + ELU + block partial sums ----------------
__global__ __launch_bounds__(256) void agg1_kernel(
    const __hip_bfloat16* __restrict__ ftb1, const float* __restrict__ resf1,
    const int* __restrict__ row, const int* __restrict__ srcs,
    const float* __restrict__ el, const float* __restrict__ er,
    const float* __restrict__ b1, float* __restrict__ part)
{
    __shared__ float red[4][256];
    int t = threadIdx.x;
    int lane = t & 63, wid = t >> 6;
    int n = blockIdx.x * 4 + wid;
    int hh = lane >> 5, dim = lane * 8;
    int e0 = row[n], e1 = row[n + 1];
    float er0v = er[n * 2 + 0], er1v = er[n * 2 + 1];

    float acc[8] = {0.f, 0.f, 0.f, 0.f, 0.f, 0.f, 0.f, 0.f};
    float ts0 = 0.f, ts1 = 0.f;
    for (int base = e0; base < e1; base += 64) {
        int c = min(64, e1 - base);
        float w0 = 0.f, w1 = 0.f;
        int sm = -1;
        if (lane < c) {
            sm = srcs[base + lane];
            float v0 = el[sm * 2 + 0] + er0v; v0 = v0 > 0.f ? v0 : NEG_SLOPE * v0;
            float v1 = el[sm * 2 + 1] + er1v; v1 = v1 > 0.f ? v1 : NEG_SLOPE * v1;
            w0 = __expf(v0); w1 = __expf(v1);
        }
        ts0 += w0; ts1 += w1;
        int i = 0;
        for (; i + 4 <= c; i += 4) {
            int sA = __shfl(sm, i),     sB = __shfl(sm, i + 1);
            int sC = __shfl(sm, i + 2), sD = __shfl(sm, i + 3);
            float a0A = __shfl(w0, i),     a1A = __shfl(w1, i);
            float a0B = __shfl(w0, i + 1), a1B = __shfl(w1, i + 1);
            float a0C = __shfl(w0, i + 2), a1C = __shfl(w1, i + 2);
            float a0D = __shfl(w0, i + 3), a1D = __shfl(w1, i + 3);
            float aA = hh ? a1A : a0A, aB = hh ? a1B : a0B;
            float aC = hh ? a1C : a0C, aD = hh ? a1D : a0D;
            bf16x8 vA = *(const bf16x8*)((const short*)ftb1 + (size_t)sA * 512 + dim);
            bf16x8 vB = *(const bf16x8*)((const short*)ftb1 + (size_t)sB * 512 + dim);
            bf16x8 vC = *(const bf16x8*)((const short*)ftb1 + (size_t)sC * 512 + dim);
            bf16x8 vD = *(const bf16x8*)((const short*)ftb1 + (size_t)sD * 512 + dim);
#pragma unroll
            for (int j = 0; j < 8; j++) {
                acc[j] += aA * b2f(vA[j]) + aB * b2f(vB[j]) + aC * b2f(vC[j]) + aD * b2f(vD[j]);
            }
        }
        for (; i < c; i++) {
            int s = __shfl(sm, i);
            float a0 = __shfl(w0, i), a1 = __shfl(w1, i);
            float a = hh ? a1 : a0;
            bf16x8 v = *(const bf16x8*)((const short*)ftb1 + (size_t)s * 512 + dim);
#pragma unroll
            for (int j = 0; j < 8; j++) acc[j] += a * b2f(v[j]);
        }
    }
#pragma unroll
    for (int d = 32; d; d >>= 1) { ts0 += __shfl_xor(ts0, d); ts1 += __shfl_xor(ts1, d); }
    float s = hh ? ts1 : ts0;
    float invv = s > 0.f ? 1.f / s : 0.f;

    const float* resp = resf1 + (size_t)n * 512 + dim;
    float r[8];
#pragma unroll
    for (int j = 0; j < 8; j++)
        r[j] = acc[j] * invv + resp[j] + b1[dim + j];
    float v[8];
#pragma unroll
    for (int j = 0; j < 8; j++) {
        float o = __shfl_xor(r[j], 32);
        v[j] = 0.5f * (r[j] + o);
    }
    if (lane < 32) {
#pragma unroll
        for (int j = 0; j < 8; j++) {
            float x = v[j];
            x = x > 0.f ? x : (__expf(x) - 1.f);
            red[wid][lane * 8 + j] = x;
        }
    }
    __syncthreads();
    part[(size_t)blockIdx.x * 256 + t] = red[0][t] + red[1][t] + red[2][t] + red[3][t];
}

// ---------------- readout: combine block partials + 3-layer MLP ----------------
__global__ __launch_bounds__(256) void readout2_kernel(
    const float* __restrict__ part,
    const float* __restrict__ mW0, const float* __restrict__ mb0,
    const float* __restrict__ mW1, const float* __restrict__ mb1,
    const float* __restrict__ mW2, const float* __restrict__ mb2,
    float* __restrict__ out)
{
    __shared__ float hg[256];
    __shared__ float x1[128];
    __shared__ float x2[64];
    int g = blockIdx.x, t = threadIdx.x;
    float s = 0.f;
    for (int c = 0; c < 128; c++) s += part[(size_t)(g * 128 + c) * 256 + t];
    hg[t] = s * (1.f / (float)NPGC);
    __syncthreads();
    if (t < 128) {
        float a = mb0[t];
        for (int k = 0; k < 256; k++) a += hg[k] * mW0[k * 128 + t];
        x1[t] = fmaxf(a, 0.f);
    }
    __syncthreads();
    if (t < 64) {
        float a = mb1[t];
        for (int k = 0; k < 128; k++) a += x1[k] * mW1[k * 64 + t];
        x2[t] = fmaxf(a, 0.f);
    }
    __syncthreads();
    if (t < 2) {
        float a = mb2[t];
        for (int k = 0; k < 64; k++) a += x2[k] * mW2[k * 2 + t];
        out[g * 2 + t] = a;
    }
}

extern "C" void kernel_launch(void* const* d_in, const int* in_sizes, int n_in,
                              void* d_out, int out_size, void* d_ws, size_t ws_size,
                              hipStream_t stream)
{
    const float* feat   = (const float*)d_in[0];
    const float* aa_emb = (const float*)d_in[1];
    const float* W0     = (const float*)d_in[2];
    const float* al0    = (const float*)d_in[3];
    const float* ar0    = (const float*)d_in[4];
    const float* res0   = (const float*)d_in[5];
    const float* b0     = (const float*)d_in[6];
    const float* W1     = (const float*)d_in[7];
    const float* al1    = (const float*)d_in[8];
    const float* ar1    = (const float*)d_in[9];
    const float* res1   = (const float*)d_in[10];
    const float* b1     = (const float*)d_in[11];
    const float* mW0    = (const float*)d_in[12];
    const float* mb0    = (const float*)d_in[13];
    const float* mW1    = (const float*)d_in[14];
    const float* mb1    = (const float*)d_in[15];
    const float* mW2    = (const float*)d_in[16];
    const float* mb2    = (const float*)d_in[17];
    const int* ref_aa   = (const int*)d_in[18];
    const int* alt_aa   = (const int*)d_in[19];
    const int* src      = (const int*)d_in[20];
    const int* dst      = (const int*)d_in[21];
    const int* graph_id = (const int*)d_in[22];
    float* out = (float*)d_out;

    size_t off = 0;
    auto alloc = [&](size_t bytes) -> void* {
        void* p = (char*)d_ws + off;
        off += (bytes + 255) & ~(size_t)255;
        return p;
    };
    __hip_bfloat16* h    = (__hip_bfloat16*)alloc((size_t)NN * 320 * 2);
    __hip_bfloat16* wt0  = (__hip_bfloat16*)alloc((size_t)256 * 320 * 2);
    __hip_bfloat16* wt1  = (__hip_bfloat16*)alloc((size_t)1024 * 128 * 2);
    __hip_bfloat16* ftb0 = (__hip_bfloat16*)alloc((size_t)NN * 128 * 2);
    float* resf0  = (float*)alloc((size_t)NN * 128 * 4);
    __hip_bfloat16* h1b  = (__hip_bfloat16*)alloc((size_t)NN * 128 * 2);
    __hip_bfloat16* ftb1 = (__hip_bfloat16*)alloc((size_t)NN * 512 * 2);
    float* resf1  = (float*)alloc((size_t)NN * 512 * 4);
    float* el0    = (float*)alloc((size_t)NN * 2 * 4);
    float* er0    = (float*)alloc((size_t)NN * 2 * 4);
    float* el1    = (float*)alloc((size_t)NN * 2 * 4);
    float* er1    = (float*)alloc((size_t)NN * 2 * 4);
    int* deg      = (int*)alloc((size_t)NN * 4);
    int* row      = (int*)alloc((size_t)(NN + 1) * 4);
    int* cursor   = (int*)alloc((size_t)NN * 4);
    int* srcs     = (int*)alloc((size_t)EE * 4);
    float* part   = (float*)alloc((size_t)(NN / 4) * 256 * 4);

    (void)in_sizes; (void)n_in; (void)out_size; (void)ws_size;

    // k1: build_h + zero deg + both weight transposes
    prep_kernel<<<NN + 256 + 1024, 320, 0, stream>>>(
        feat, aa_emb, ref_aa, alt_aa, graph_id, h, deg, W0, res0, W1, res1, wt0, wt1);
    // k2: gemm0 U deg count
    gemm0_deg_kernel<<<2048, 256, 0, stream>>>(h, wt0, ftb0, resf0, dst, deg);
    // k3: scan U elr0
    scan_elr0_kernel<<<1 + 8192, 256, 0, stream>>>(deg, row, cursor, ftb0, al0, ar0, el0, er0);
    // k4: scatter
    scatter_kernel<<<EE / 256, 256, 0, stream>>>(src, dst, cursor, srcs);
    // k5: layer0 aggregation
    agg0_kernel<<<NN / 4, 256, 0, stream>>>(ftb0, resf0, row, srcs, el0, er0, b0, h1b);
    // k6: gemm1
    gemm1_kernel<<<dim3(128, 8), 256, 0, stream>>>(h1b, wt1, ftb1, resf1);
    // k7: elr1
    elr1_kernel<<<NN / 4, 256, 0, stream>>>(ftb1, al1, ar1, el1, er1);
    // k8: layer1 aggregation + block partial readout
    agg1_kernel<<<NN / 4, 256, 0, stream>>>(ftb1, resf1, row, srcs, el1, er1, b1, part);
    // k9: final readout + MLP
    readout2_kernel<<<GG, 256, 0, stream>>>(part, mW0, mb0, mW1, mb1, mW2, mb2, out);
}

// Round 11
// 147.921 us; speedup vs baseline: 3.7324x; 1.0361x over previous
//
#include <hip/hip_runtime.h>
#include <hip/hip_bf16.h>

#define NN 16384
#define EE 262144
#define GG 32
#define NPGC 512
#define NEG_SLOPE 0.2f

typedef __attribute__((ext_vector_type(8))) short bf16x8;
typedef __attribute__((ext_vector_type(4))) float f32x4;

__device__ __forceinline__ float b2f(short s) {
    union { float f; unsigned u; } c;
    c.u = ((unsigned)(unsigned short)s) << 16;
    return c.f;
}

__device__ __forceinline__ short f2b(float f) {
    __hip_bfloat16 b = __float2bfloat16(f);
    short r;
    __builtin_memcpy(&r, &b, 2);
    return r;
}

// ---------------- k1 prep: build_h (+zero deg) U wtrans(layer0) U wtrans(layer1) ----------------
__global__ __launch_bounds__(320) void prep_kernel(
    const float* __restrict__ feat, const float* __restrict__ aa_emb,
    const int* __restrict__ ref_aa, const int* __restrict__ alt_aa,
    const int* __restrict__ graph_id, __hip_bfloat16* __restrict__ h,
    int* __restrict__ deg,
    const float* __restrict__ W0, const float* __restrict__ R0,
    const float* __restrict__ W1, const float* __restrict__ R1,
    __hip_bfloat16* __restrict__ wt0, __hip_bfloat16* __restrict__ wt1)
{
    int b = blockIdx.x, t = threadIdx.x;
    if (b < NN) {
        int n = b;
        if (t == 0) deg[n] = 0;
        float v;
        if (t < 64) {
            int ra = ref_aa[n], ga = alt_aa[graph_id[n]];
            v = aa_emb[ra * 64 + t] * aa_emb[ga * 64 + t];
        } else {
            v = feat[(size_t)n * 256 + (t - 64)];
        }
        h[(size_t)n * 320 + t] = __float2bfloat16(v);
    } else if (b < NN + 256) {
        int c = b - NN;   // layer0 col, K=320 == blockDim
        float v = (c < 128) ? W0[(size_t)t * 128 + c] : R0[(size_t)t * 128 + (c - 128)];
        wt0[(size_t)c * 320 + t] = __float2bfloat16(v);
    } else {
        int cc = b - NN - 256;  // layer1 col, K=128
        if (t < 128) {
            float v = (cc < 512) ? W1[(size_t)t * 512 + cc] : R1[(size_t)t * 512 + (cc - 512)];
            wt1[(size_t)cc * 128 + t] = __float2bfloat16(v);
        }
    }
}

// ---------------- MFMA GEMM body: split bf16 output [ftb | resb] ----------------
template<int FR, int C1, int KTOT>
__device__ __forceinline__ void gemm_body(
    const __hip_bfloat16* __restrict__ A, const __hip_bfloat16* __restrict__ Bt,
    __hip_bfloat16* __restrict__ ftb, __hip_bfloat16* __restrict__ resb,
    int bx, int by, short* lds)
{
    constexpr int BM = 32 * FR;
    short* As = lds;
    short* Bs = lds + BM * 64;
    int t = threadIdx.x;
    int wid = t >> 6, lane = t & 63;
    int wr = wid >> 1, wc = wid & 1;
    int row0 = bx * BM, col0 = by * BM;

    f32x4 acc[FR][FR];
#pragma unroll
    for (int m = 0; m < FR; m++)
#pragma unroll
        for (int n = 0; n < FR; n++) acc[m][n] = (f32x4){0.f, 0.f, 0.f, 0.f};

    for (int kk = 0; kk < KTOT; kk += 64) {
        __syncthreads();
#pragma unroll
        for (int c = t; c < BM * 8; c += 256) {
            int row = c >> 3, slot = c & 7;
            int sw = (slot ^ (row & 7)) * 8;
            bf16x8 va = *(const bf16x8*)(A + (size_t)(row0 + row) * KTOT + kk + slot * 8);
            *(bf16x8*)(&As[row * 64 + sw]) = va;
            bf16x8 vb = *(const bf16x8*)(Bt + (size_t)(col0 + row) * KTOT + kk + slot * 8);
            *(bf16x8*)(&Bs[row * 64 + sw]) = vb;
        }
        __syncthreads();
#pragma unroll
        for (int ks = 0; ks < 2; ks++) {
            int kslot = ks * 4 + (lane >> 4);
            bf16x8 a[FR], bfr[FR];
#pragma unroll
            for (int m = 0; m < FR; m++) {
                int row = wr * FR * 16 + m * 16 + (lane & 15);
                a[m] = *(const bf16x8*)(&As[row * 64 + ((kslot ^ (row & 7)) * 8)]);
            }
#pragma unroll
            for (int n = 0; n < FR; n++) {
                int col = wc * FR * 16 + n * 16 + (lane & 15);
                bfr[n] = *(const bf16x8*)(&Bs[col * 64 + ((kslot ^ (col & 7)) * 8)]);
            }
#pragma unroll
            for (int m = 0; m < FR; m++)
#pragma unroll
                for (int n = 0; n < FR; n++)
                    acc[m][n] = __builtin_amdgcn_mfma_f32_16x16x32_bf16(a[m], bfr[n], acc[m][n], 0, 0, 0);
        }
    }

#pragma unroll
    for (int m = 0; m < FR; m++)
#pragma unroll
        for (int n = 0; n < FR; n++) {
            int colg = col0 + wc * FR * 16 + n * 16 + (lane & 15);
            int rbase = row0 + wr * FR * 16 + m * 16 + (lane >> 4) * 4;
#pragma unroll
            for (int r = 0; r < 4; r++) {
                float v = acc[m][n][r];
                int rg = rbase + r;
                if (colg < C1) ftb[(size_t)rg * C1 + colg] = __float2bfloat16(v);
                else           resb[(size_t)rg * C1 + (colg - C1)] = __float2bfloat16(v);
            }
        }
}

// ---------------- k2: gemm0 (blocks 0..1023) U deg count (blocks 1024..2047) ----------------
__global__ __launch_bounds__(256) void gemm0_deg_kernel(
    const __hip_bfloat16* __restrict__ A, const __hip_bfloat16* __restrict__ Bt,
    __hip_bfloat16* __restrict__ ftb, __hip_bfloat16* __restrict__ resb,
    const int* __restrict__ dst, int* __restrict__ deg)
{
    __shared__ short lds[2 * 64 * 64];
    int b = blockIdx.x;
    if (b < 1024) {
        gemm_body<2, 128, 320>(A, Bt, ftb, resb, b & 255, b >> 8, lds);
    } else {
        int i = (b - 1024) * 256 + threadIdx.x;
        if (i < EE) atomicAdd(&deg[dst[i]], 1);
    }
}

// ---------------- gemm1 standalone ----------------
__global__ __launch_bounds__(256) void gemm1_kernel(
    const __hip_bfloat16* __restrict__ A, const __hip_bfloat16* __restrict__ Bt,
    __hip_bfloat16* __restrict__ ftb, __hip_bfloat16* __restrict__ resb)
{
    __shared__ short lds[2 * 128 * 64];
    gemm_body<4, 512, 128>(A, Bt, ftb, resb, blockIdx.x, blockIdx.y, lds);
}

// ---------------- k3: scan (block 0) U elr0 (blocks 1..8192) ----------------
__global__ __launch_bounds__(256) void scan_elr0_kernel(
    const int* __restrict__ deg, int* __restrict__ row, int* __restrict__ cursor,
    const __hip_bfloat16* __restrict__ ftb,
    const float* __restrict__ al, const float* __restrict__ ar,
    float* __restrict__ el, float* __restrict__ er)
{
    int b = blockIdx.x, t = threadIdx.x;
    if (b == 0) {
        __shared__ int part[256];
        __shared__ int pref[257];
        int base = t * 64;
        int s = 0;
        for (int i = 0; i < 64; i++) s += deg[base + i];
        part[t] = s;
        __syncthreads();
        if (t == 0) {
            int a = 0;
            for (int i = 0; i < 256; i++) { pref[i] = a; a += part[i]; }
            pref[256] = a;
        }
        __syncthreads();
        int a = pref[t];
        for (int i = 0; i < 64; i++) {
            row[base + i] = a; cursor[base + i] = a;
            a += deg[base + i];
        }
        if (t == 0) row[NN] = pref[256];
    } else {
        int gid = (b - 1) * 256 + t;
        int wv = gid >> 6, lane = gid & 63;
        int n = wv >> 1, hh = wv & 1;
        if (n >= NN) return;
        float f = b2f(((const short*)ftb)[(size_t)n * 128 + hh * 64 + lane]);
        float sl = f * al[hh * 64 + lane];
        float sr = f * ar[hh * 64 + lane];
#pragma unroll
        for (int d = 32; d; d >>= 1) { sl += __shfl_xor(sl, d); sr += __shfl_xor(sr, d); }
        if (lane == 0) { el[n * 2 + hh] = sl; er[n * 2 + hh] = sr; }
    }
}

// scatter src node ids directly into dst-sorted order
__global__ __launch_bounds__(256) void scatter_kernel(
    const int* __restrict__ src, const int* __restrict__ dst,
    int* __restrict__ cursor, int* __restrict__ srcs)
{
    int i = blockIdx.x * 256 + threadIdx.x;
    if (i < EE) {
        int p = atomicAdd(&cursor[dst[i]], 1);
        srcs[p] = src[i];
    }
}

// ---------------- layer1 el/er: one wave per node, vectorized ----------------
__global__ __launch_bounds__(256) void elr1_kernel(
    const __hip_bfloat16* __restrict__ ftb,
    const float* __restrict__ al, const float* __restrict__ ar,
    float* __restrict__ el, float* __restrict__ er)
{
    int wv = (blockIdx.x * 256 + threadIdx.x) >> 6;
    int lane = threadIdx.x & 63;
    if (wv >= NN) return;
    int n = wv, hh = lane >> 5, dim = lane * 8;
    bf16x8 v = *(const bf16x8*)((const short*)ftb + (size_t)n * 512 + dim);
    float sl = 0.f, sr = 0.f;
#pragma unroll
    for (int j = 0; j < 8; j++) {
        float f = b2f(v[j]);
        sl += f * al[dim + j];
        sr += f * ar[dim + j];
    }
#pragma unroll
    for (int d = 16; d; d >>= 1) { sl += __shfl_xor(sl, d); sr += __shfl_xor(sr, d); }
    if ((lane & 31) == 0) { el[n * 2 + hh] = sl; er[n * 2 + hh] = sr; }
}

// ---------------- layer0 fused softmax+aggregation -> h1 (bf16) [R5 numerics] ----------------
__global__ __launch_bounds__(256) void agg0_kernel(
    const __hip_bfloat16* __restrict__ ftb0, const __hip_bfloat16* __restrict__ resb0,
    const int* __restrict__ row, const int* __restrict__ srcs,
    const float* __restrict__ el, const float* __restrict__ er,
    const float* __restrict__ b0, __hip_bfloat16* __restrict__ h1)
{
    int wv = (blockIdx.x * 256 + threadIdx.x) >> 6;
    int lane = threadIdx.x & 63;
    if (wv >= NN) return;
    int n = wv;
    int eo = lane >> 4, vo = lane & 15;
    int hh = vo >> 3, dim = vo * 8;
    int e0 = row[n], e1 = row[n + 1];
    float er0v = er[n * 2 + 0], er1v = er[n * 2 + 1];

    float acc[8] = {0.f, 0.f, 0.f, 0.f, 0.f, 0.f, 0.f, 0.f};
    float ts0 = 0.f, ts1 = 0.f;
    for (int base = e0; base < e1; base += 64) {
        int c = min(64, e1 - base);
        float w0 = 0.f, w1 = 0.f;
        int sm = -1;
        if (lane < c) {
            sm = srcs[base + lane];
            float v0 = el[sm * 2 + 0] + er0v; v0 = v0 > 0.f ? v0 : NEG_SLOPE * v0;
            float v1 = el[sm * 2 + 1] + er1v; v1 = v1 > 0.f ? v1 : NEG_SLOPE * v1;
            w0 = __expf(v0); w1 = __expf(v1);
        }
        ts0 += w0; ts1 += w1;
        for (int i = eo; i < c; i += 4) {
            int s = __shfl(sm, i);
            float a0 = __shfl(w0, i), a1 = __shfl(w1, i);
            float a = hh ? a1 : a0;
            bf16x8 v = *(const bf16x8*)((const short*)ftb0 + (size_t)s * 128 + dim);
#pragma unroll
            for (int j = 0; j < 8; j++) acc[j] += a * b2f(v[j]);
        }
    }
#pragma unroll
    for (int d = 32; d; d >>= 1) { ts0 += __shfl_xor(ts0, d); ts1 += __shfl_xor(ts1, d); }
#pragma unroll
    for (int j = 0; j < 8; j++) acc[j] += __shfl_xor(acc[j], 16);
#pragma unroll
    for (int j = 0; j < 8; j++) acc[j] += __shfl_xor(acc[j], 32);
    if (eo == 0) {
        float s = hh ? ts1 : ts0;
        float invv = s > 0.f ? 1.f / s : 0.f;
        bf16x8 res = *(const bf16x8*)((const short*)resb0 + (size_t)n * 128 + dim);
        bf16x8 o;
#pragma unroll
        for (int j = 0; j < 8; j++) {
            float r = acc[j] * invv + b2f(res[j]) + b0[dim + j];
            r = r > 0.f ? r : (__expf(r) - 1.f);
            o[j] = f2b(r);
        }
        *(bf16x8*)((short*)h1 + (size_t)n * 128 + dim) = o;
    }
}

// ---------------- layer1 fused softmax+agg + head-mean + ELU + block partial sums ----------------
__global__ __launch_bounds__(256) void agg1_kernel(
    const __hip_bfloat16* __restrict__ ftb1, const __hip_bfloat16* __restrict__ resb1,
    const int* __restrict__ row, const int* __restrict__ srcs,
    const float* __restrict__ el, const float* __restrict__ er,
    const float* __restrict__ b1, float* __restrict__ part)
{
    __shared__ float red[4][256];
    int t = threadIdx.x;
    int lane = t & 63, wid = t >> 6;
    int n = blockIdx.x * 4 + wid;
    int hh = lane >> 5, dim = lane * 8;
    int e0 = row[n], e1 = row[n + 1];
    float er0v = er[n * 2 + 0], er1v = er[n * 2 + 1];

    float acc[8] = {0.f, 0.f, 0.f, 0.f, 0.f, 0.f, 0.f, 0.f};
    float ts0 = 0.f, ts1 = 0.f;
    for (int base = e0; base < e1; base += 64) {
        int c = min(64, e1 - base);
        float w0 = 0.f, w1 = 0.f;
        int sm = -1;
        if (lane < c) {
            sm = srcs[base + lane];
            float v0 = el[sm * 2 + 0] + er0v; v0 = v0 > 0.f ? v0 : NEG_SLOPE * v0;
            float v1 = el[sm * 2 + 1] + er1v; v1 = v1 > 0.f ? v1 : NEG_SLOPE * v1;
            w0 = __expf(v0); w1 = __expf(v1);
        }
        ts0 += w0; ts1 += w1;
        int i = 0;
        for (; i + 4 <= c; i += 4) {
            int sA = __shfl(sm, i),     sB = __shfl(sm, i + 1);
            int sC = __shfl(sm, i + 2), sD = __shfl(sm, i + 3);
            float a0A = __shfl(w0, i),     a1A = __shfl(w1, i);
            float a0B = __shfl(w0, i + 1), a1B = __shfl(w1, i + 1);
            float a0C = __shfl(w0, i + 2), a1C = __shfl(w1, i + 2);
            float a0D = __shfl(w0, i + 3), a1D = __shfl(w1, i + 3);
            float aA = hh ? a1A : a0A, aB = hh ? a1B : a0B;
            float aC = hh ? a1C : a0C, aD = hh ? a1D : a0D;
            bf16x8 vA = *(const bf16x8*)((const short*)ftb1 + (size_t)sA * 512 + dim);
            bf16x8 vB = *(const bf16x8*)((const short*)ftb1 + (size_t)sB * 512 + dim);
            bf16x8 vC = *(const bf16x8*)((const short*)ftb1 + (size_t)sC * 512 + dim);
            bf16x8 vD = *(const bf16x8*)((const short*)ftb1 + (size_t)sD * 512 + dim);
#pragma unroll
            for (int j = 0; j < 8; j++) {
                acc[j] += aA * b2f(vA[j]) + aB * b2f(vB[j]) + aC * b2f(vC[j]) + aD * b2f(vD[j]);
            }
        }
        for (; i < c; i++) {
            int s = __shfl(sm, i);
            float a0 = __shfl(w0, i), a1 = __shfl(w1, i);
            float a = hh ? a1 : a0;
            bf16x8 v = *(const bf16x8*)((const short*)ftb1 + (size_t)s * 512 + dim);
#pragma unroll
            for (int j = 0; j < 8; j++) acc[j] += a * b2f(v[j]);
        }
    }
#pragma unroll
    for (int d = 32; d; d >>= 1) { ts0 += __shfl_xor(ts0, d); ts1 += __shfl_xor(ts1, d); }
    float s = hh ? ts1 : ts0;
    float invv = s > 0.f ? 1.f / s : 0.f;

    bf16x8 res = *(const bf16x8*)((const short*)resb1 + (size_t)n * 512 + dim);
    float r[8];
#pragma unroll
    for (int j = 0; j < 8; j++)
        r[j] = acc[j] * invv + b2f(res[j]) + b1[dim + j];
    float v[8];
#pragma unroll
    for (int j = 0; j < 8; j++) {
        float o = __shfl_xor(r[j], 32);
        v[j] = 0.5f * (r[j] + o);
    }
    if (lane < 32) {
#pragma unroll
        for (int j = 0; j < 8; j++) {
            float x = v[j];
            x = x > 0.f ? x : (__expf(x) - 1.f);
            red[wid][lane * 8 + j] = x;
        }
    }
    __syncthreads();
    part[(size_t)blockIdx.x * 256 + t] = red[0][t] + red[1][t] + red[2][t] + red[3][t];
}

// ---------------- readout: combine block partials + 3-layer MLP ----------------
__global__ __launch_bounds__(256) void readout2_kernel(
    const float* __restrict__ part,
    const float* __restrict__ mW0, const float* __restrict__ mb0,
    const float* __restrict__ mW1, const float* __restrict__ mb1,
    const float* __restrict__ mW2, const float* __restrict__ mb2,
    float* __restrict__ out)
{
    __shared__ float hg[256];
    __shared__ float x1[128];
    __shared__ float x2[64];
    int g = blockIdx.x, t = threadIdx.x;
    float s = 0.f;
    for (int c = 0; c < 128; c++) s += part[(size_t)(g * 128 + c) * 256 + t];
    hg[t] = s * (1.f / (float)NPGC);
    __syncthreads();
    if (t < 128) {
        float a = mb0[t];
        for (int k = 0; k < 256; k++) a += hg[k] * mW0[k * 128 + t];
        x1[t] = fmaxf(a, 0.f);
    }
    __syncthreads();
    if (t < 64) {
        float a = mb1[t];
        for (int k = 0; k < 128; k++) a += x1[k] * mW1[k * 64 + t];
        x2[t] = fmaxf(a, 0.f);
    }
    __syncthreads();
    if (t < 2) {
        float a = mb2[t];
        for (int k = 0; k < 64; k++) a += x2[k] * mW2[k * 2 + t];
        out[g * 2 + t] = a;
    }
}

extern "C" void kernel_launch(void* const* d_in, const int* in_sizes, int n_in,
                              void* d_out, int out_size, void* d_ws, size_t ws_size,
                              hipStream_t stream)
{
    const float* feat   = (const float*)d_in[0];
    const float* aa_emb = (const float*)d_in[1];
    const float* W0     = (const float*)d_in[2];
    const float* al0    = (const float*)d_in[3];
    const float* ar0    = (const float*)d_in[4];
    const float* res0   = (const float*)d_in[5];
    const float* b0     = (const float*)d_in[6];
    const float* W1     = (const float*)d_in[7];
    const float* al1    = (const float*)d_in[8];
    const float* ar1    = (const float*)d_in[9];
    const float* res1   = (const float*)d_in[10];
    const float* b1     = (const float*)d_in[11];
    const float* mW0    = (const float*)d_in[12];
    const float* mb0    = (const float*)d_in[13];
    const float* mW1    = (const float*)d_in[14];
    const float* mb1    = (const float*)d_in[15];
    const float* mW2    = (const float*)d_in[16];
    const float* mb2    = (const float*)d_in[17];
    const int* ref_aa   = (const int*)d_in[18];
    const int* alt_aa   = (const int*)d_in[19];
    const int* src      = (const int*)d_in[20];
    const int* dst      = (const int*)d_in[21];
    const int* graph_id = (const int*)d_in[22];
    float* out = (float*)d_out;

    size_t off = 0;
    auto alloc = [&](size_t bytes) -> void* {
        void* p = (char*)d_ws + off;
        off += (bytes + 255) & ~(size_t)255;
        return p;
    };
    __hip_bfloat16* h     = (__hip_bfloat16*)alloc((size_t)NN * 320 * 2);
    __hip_bfloat16* wt0   = (__hip_bfloat16*)alloc((size_t)256 * 320 * 2);
    __hip_bfloat16* wt1   = (__hip_bfloat16*)alloc((size_t)1024 * 128 * 2);
    __hip_bfloat16* ftb0  = (__hip_bfloat16*)alloc((size_t)NN * 128 * 2);
    __hip_bfloat16* resb0 = (__hip_bfloat16*)alloc((size_t)NN * 128 * 2);
    __hip_bfloat16* h1b   = (__hip_bfloat16*)alloc((size_t)NN * 128 * 2);
    __hip_bfloat16* ftb1  = (__hip_bfloat16*)alloc((size_t)NN * 512 * 2);
    __hip_bfloat16* resb1 = (__hip_bfloat16*)alloc((size_t)NN * 512 * 2);
    float* el0    = (float*)alloc((size_t)NN * 2 * 4);
    float* er0    = (float*)alloc((size_t)NN * 2 * 4);
    float* el1    = (float*)alloc((size_t)NN * 2 * 4);
    float* er1    = (float*)alloc((size_t)NN * 2 * 4);
    int* deg      = (int*)alloc((size_t)NN * 4);
    int* row      = (int*)alloc((size_t)(NN + 1) * 4);
    int* cursor   = (int*)alloc((size_t)NN * 4);
    int* srcs     = (int*)alloc((size_t)EE * 4);
    float* part   = (float*)alloc((size_t)(NN / 4) * 256 * 4);

    (void)in_sizes; (void)n_in; (void)out_size; (void)ws_size;

    // k1: build_h + zero deg + both weight transposes
    prep_kernel<<<NN + 256 + 1024, 320, 0, stream>>>(
        feat, aa_emb, ref_aa, alt_aa, graph_id, h, deg, W0, res0, W1, res1, wt0, wt1);
    // k2: gemm0 U deg count
    gemm0_deg_kernel<<<2048, 256, 0, stream>>>(h, wt0, ftb0, resb0, dst, deg);
    // k3: scan U elr0
    scan_elr0_kernel<<<1 + 8192, 256, 0, stream>>>(deg, row, cursor, ftb0, al0, ar0, el0, er0);
    // k4: scatter
    scatter_kernel<<<EE / 256, 256, 0, stream>>>(src, dst, cursor, srcs);
    // k5: layer0 aggregation
    agg0_kernel<<<NN / 4, 256, 0, stream>>>(ftb0, resb0, row, srcs, el0, er0, b0, h1b);
    // k6: gemm1
    gemm1_kernel<<<dim3(128, 8), 256, 0, stream>>>(h1b, wt1, ftb1, resb1);
    // k7: elr1
    elr1_kernel<<<NN / 4, 256, 0, stream>>>(ftb1, al1, ar1, el1, er1);
    // k8: layer1 aggregation + block partial readout
    agg1_kernel<<<NN / 4, 256, 0, stream>>>(ftb1, resb1, row, srcs, el1, er1, b1, part);
    // k9: final readout + MLP
    readout2_kernel<<<GG, 256, 0, stream>>>(part, mW0, mb0, mW1, mb1, mW2, mb2, out);
}